// Round 17
// baseline (8383.125 us; speedup 1.0000x reference)
//
#include <hip/hip_runtime.h>
#include <hip/hip_bf16.h>
#include <stdint.h>

#define BN 8192
#define TT 128
#define II 64
#define HH 256
#define GG 768
#define KK 12
#define KM_ITERS_N 25
#define UB 64
#define UPB (BN/UB)
#define KSTEPS 20

typedef __attribute__((ext_vector_type(8))) _Float16 f16x8;
typedef __attribute__((ext_vector_type(4))) _Float16 f16x4;
typedef __attribute__((ext_vector_type(16))) float f32x16;

// ---------------- threefry2x32 (JAX-exact) ----------------
__device__ __forceinline__ uint32_t rotl32(uint32_t v, int d) {
  return (v << d) | (v >> (32 - d));
}
__device__ __forceinline__ void tf2x32(uint32_t k0, uint32_t k1,
                                       uint32_t x0, uint32_t x1,
                                       uint32_t& o0, uint32_t& o1) {
  uint32_t ks2 = k0 ^ k1 ^ 0x1BD11BDAu;
  x0 += k0; x1 += k1;
#define TFR(r) { x0 += x1; x1 = rotl32(x1, r); x1 ^= x0; }
  TFR(13); TFR(15); TFR(26); TFR(6);   x0 += k1;  x1 += ks2 + 1u;
  TFR(17); TFR(29); TFR(16); TFR(24);  x0 += ks2; x1 += k0 + 2u;
  TFR(13); TFR(15); TFR(26); TFR(6);   x0 += k0;  x1 += k1 + 3u;
  TFR(17); TFR(29); TFR(16); TFR(24);  x0 += k1;  x1 += ks2 + 4u;
  TFR(13); TFR(15); TFR(26); TFR(6);   x0 += ks2; x1 += k0 + 5u;
#undef TFR
  o0 = x0; o1 = x1;
}
__device__ __forceinline__ float bits_to_unit(uint32_t bits) {
  uint32_t u = (bits >> 9) | 0x3f800000u;
  return __uint_as_float(u) - 1.0f;
}

// ---------------- fp16 2-plane split (residual scaled by 4096) ----------------
#define RSCL 4096.f
#define RINV (1.f / 4096.f)
__device__ __forceinline__ void split2h(float v, _Float16& m, _Float16& r) {
  m = (_Float16)v;
  r = (_Float16)((v - (float)m) * RSCL);
}

// ---------------- fast gates (exp2-based; v_exp_f32 native) ----------------
__device__ __forceinline__ float sigm_f(float u) {
  return 1.f / (1.f + exp2f(u * -1.4426950408889634f));
}
__device__ __forceinline__ float tanh_f(float u) {
  return 1.f - 2.f / (1.f + exp2f(u * 2.8853900817779268f));
}

// ---------------- weight pack: [ks 20][cf 24][p 2][lane 64]*16B ----------------
__global__ void k_pack4(const float* __restrict__ wih, const float* __restrict__ whh,
                        char* __restrict__ wpk4) {
  int u = blockIdx.x * 256 + threadIdx.x;
  if (u >= KSTEPS * 24 * 2 * 64) return;
  int lane = u & 63; int rest = u >> 6;
  int p = rest & 1; rest >>= 1;
  int cf = rest % 24; int ks = rest / 24;
  int l31 = lane & 31, khalf = lane >> 5;
  int col = cf * 32 + l31;
  int gate = col >> 8, d = col & 255;
  int grow = gate * 256 + d;
  _Float16 s[8];
#pragma unroll
  for (int j = 0; j < 8; ++j) {
    int k = khalf * 8 + j;
    float wv = (ks < 4) ? wih[grow * II + ks * 16 + k]
                        : whh[grow * HH + (ks - 4) * 16 + k];
    _Float16 m, r;
    split2h(wv, m, r);
    s[j] = p ? r : m;
  }
  *(f16x8*)(wpk4 + (size_t)u * 16) = *(f16x8*)s;
}

// ---------------- persistent MFMA GRU v9 (16 waves, kstep-split halves) ----------------
// grid 256 x 1024 thr = 16 waves. wg = w&7 (cf group), half = w>>3 (ks 0-9 / 10-19).
// LDS: h planes [0,32768); x planes [32768,40960); glh [40960,74240) = [32][260] f32;
// scratch [74240,139776): scrA [wg][32][32] f32 (32KB), scrB +32768.
// Pass1: R,Z partials; half1 -> scratch; half0 combines -> rrv,zzv.
// Pass2: N partials; half1 Nh -> scrA (after B3); half0 gates + glh.
#define GLHS 260
#define GLB 40960
#define SCRB 74240

__global__ __launch_bounds__(1024, 1) void k_gru_v9(
    const float* __restrict__ x, const char* __restrict__ wpk4,
    const float* __restrict__ bih, const float* __restrict__ bhh,
    float* __restrict__ hf_out) {
  __shared__ __align__(16) char smem[139776];
  float* glh = (float*)(smem + GLB);
  const int tid = threadIdx.x;
  const int w = tid >> 6;
  const int wg = w & 7, half = w >> 3;
  const int l = tid & 63, l31 = l & 31, kh5 = l >> 5;
  const int row0 = blockIdx.x * 32;

  {  // zero h planes (32 KB) + glh
    int4 z = {0, 0, 0, 0};
    int4* s4 = (int4*)smem;
#pragma unroll
    for (int i = 0; i < 2; ++i) s4[tid + i * 1024] = z;
    for (int i = tid; i < 32 * GLHS; i += 1024) glh[i] = 0.f;
  }
  const int d = wg * 32 + l31;
  const float biR = bih[d],          bhR = bhh[d];
  const float biZ = bih[HH + d],     bhZ = bhh[HH + d];
  const float biN = bih[2 * HH + d], bhN = bhh[2 * HH + d];

  // x prefetch: tid<512 owns (xrow, 4 k's at xko4*4)
  const int xrow = tid & 31, xko4 = (tid >> 5) & 15;
  const float* xbase = x + (size_t)(row0 + xrow) * (TT * II) + xko4 * 4;
  float4 xreg;
  if (tid < 512) xreg = *(const float4*)xbase;
  __syncthreads();

  float* scrA = (float*)(smem + SCRB);            // [wg][32][32]
  float* scrB = (float*)(smem + SCRB + 32768);    // [wg][32][32]

#define FRAG3(ACCM, ACCR, CF, KS)                                                  \
    {                                                                              \
      const char* bf = wpk4 + (((size_t)(KS) * 24 + (CF)) * 2) * 1024 +            \
                       (size_t)l * 16;                                             \
      f16x8 b0 = *(const f16x8*)(bf);                                              \
      f16x8 b1 = *(const f16x8*)(bf + 1024);                                       \
      ACCM = __builtin_amdgcn_mfma_f32_32x32x16_f16(a0, b0, ACCM, 0, 0, 0);        \
      ACCR = __builtin_amdgcn_mfma_f32_32x32x16_f16(a0, b1, ACCR, 0, 0, 0);        \
      ACCR = __builtin_amdgcn_mfma_f32_32x32x16_f16(a1, b0, ACCR, 0, 0, 0);        \
    }
#define XADDR(KS) (smem + 32768 + (size_t)((KS) * 4 + kh5) * 512 + l31 * 16)
#define HADDR(KS) (smem + (size_t)(((KS) - 4) * 4 + kh5) * 512 + l31 * 16)

  for (int t = 0; t < TT; ++t) {
    // ---- stage x planes from register (tid<512) ----
    if (tid < 512) {
      _Float16 m[4], r[4];
      split2h(xreg.x, m[0], r[0]);
      split2h(xreg.y, m[1], r[1]);
      split2h(xreg.z, m[2], r[2]);
      split2h(xreg.w, m[3], r[3]);
      int xks = xko4 >> 2, kh = (xko4 >> 1) & 1, sub = (xko4 & 1) * 8;
      char* b0 = smem + 32768 + (size_t)(xks * 4 + kh) * 512 + xrow * 16 + sub;
      *(f16x4*)b0 = *(f16x4*)m;
      *(f16x4*)(b0 + 1024) = *(f16x4*)r;
      if (t + 1 < TT) xreg = *(const float4*)(xbase + (size_t)(t + 1) * II);
    }
    __syncthreads();  // B1

    f32x16 rrv, zzv;
    // ---- pass 1: R and Z (own kstep half) ----
    {
      f32x16 aRm = (f32x16)0.f, aRr = (f32x16)0.f;
      f32x16 aZm = (f32x16)0.f, aZr = (f32x16)0.f;
      if (half == 0) {
#pragma unroll
        for (int ks = 0; ks < 4; ++ks) {
          const char* ab = XADDR(ks);
          f16x8 a0 = *(const f16x8*)(ab);
          f16x8 a1 = *(const f16x8*)(ab + 1024);
          FRAG3(aRm, aRr, wg, ks) FRAG3(aZm, aZr, 8 + wg, ks)
        }
#pragma unroll
        for (int ks = 4; ks < 10; ++ks) {
          const char* ab = HADDR(ks);
          f16x8 a0 = *(const f16x8*)(ab);
          f16x8 a1 = *(const f16x8*)(ab + 1024);
          FRAG3(aRm, aRr, wg, ks) FRAG3(aZm, aZr, 8 + wg, ks)
        }
      } else {
#pragma unroll
        for (int ks = 10; ks < KSTEPS; ++ks) {
          const char* ab = HADDR(ks);
          f16x8 a0 = *(const f16x8*)(ab);
          f16x8 a1 = *(const f16x8*)(ab + 1024);
          FRAG3(aRm, aRr, wg, ks) FRAG3(aZm, aZr, 8 + wg, ks)
        }
      }
      if (half == 1) {
#pragma unroll
        for (int j = 0; j < 16; ++j) {
          int row = (j & 3) + ((j >> 2) << 3) + kh5 * 4;
          scrA[wg * 1024 + row * 32 + l31] = aRm[j] + aRr[j] * RINV;
          scrB[wg * 1024 + row * 32 + l31] = aZm[j] + aZr[j] * RINV;
        }
      }
      __syncthreads();  // B2
      if (half == 0) {
#pragma unroll
        for (int j = 0; j < 16; ++j) {
          int row = (j & 3) + ((j >> 2) << 3) + kh5 * 4;
          float Rc = aRm[j] + aRr[j] * RINV + scrA[wg * 1024 + row * 32 + l31];
          float Zc = aZm[j] + aZr[j] * RINV + scrB[wg * 1024 + row * 32 + l31];
          rrv[j] = sigm_f(Rc + biR + bhR);
          zzv[j] = sigm_f(Zc + biZ + bhZ);
        }
      }
    }
    // ---- pass 2: N ----
    f32x16 aNxm = (f32x16)0.f, aNxr = (f32x16)0.f;
    f32x16 aNhm = (f32x16)0.f, aNhr = (f32x16)0.f;
    if (half == 0) {
#pragma unroll
      for (int ks = 0; ks < 4; ++ks) {
        const char* ab = XADDR(ks);
        f16x8 a0 = *(const f16x8*)(ab);
        f16x8 a1 = *(const f16x8*)(ab + 1024);
        FRAG3(aNxm, aNxr, 16 + wg, ks)
      }
#pragma unroll
      for (int ks = 4; ks < 10; ++ks) {
        const char* ab = HADDR(ks);
        f16x8 a0 = *(const f16x8*)(ab);
        f16x8 a1 = *(const f16x8*)(ab + 1024);
        FRAG3(aNhm, aNhr, 16 + wg, ks)
      }
    } else {
#pragma unroll
      for (int ks = 10; ks < KSTEPS; ++ks) {
        const char* ab = HADDR(ks);
        f16x8 a0 = *(const f16x8*)(ab);
        f16x8 a1 = *(const f16x8*)(ab + 1024);
        FRAG3(aNhm, aNhr, 16 + wg, ks)
      }
    }
    __syncthreads();  // B3: half0 done reading scrA/scrB; all ds_reads of planes done
    if (half == 1) {
#pragma unroll
      for (int j = 0; j < 16; ++j) {
        int row = (j & 3) + ((j >> 2) << 3) + kh5 * 4;
        scrA[wg * 1024 + row * 32 + l31] = aNhm[j] + aNhr[j] * RINV;
      }
    }
    __syncthreads();  // B4

    // ---- phase 1: gates + glh (half0 only) ----
    const bool lastT = (t == TT - 1);
    if (half == 0) {
#pragma unroll
      for (int j = 0; j < 16; ++j) {
        int row = (j & 3) + ((j >> 2) << 3) + kh5 * 4;
        float hold = glh[row * GLHS + d];
        float Nx = aNxm[j] + aNxr[j] * RINV;
        float Nh = aNhm[j] + aNhr[j] * RINV + scrA[wg * 1024 + row * 32 + l31];
        float nn = tanh_f(Nx + biN + rrv[j] * (Nh + bhN));
        float hnew = (1.f - zzv[j]) * nn + zzv[j] * hold;
        glh[row * GLHS + d] = hnew;
        if (lastT) hf_out[(size_t)(row0 + row) * HH + d] = hnew;
      }
    }
    __syncthreads();  // B5

    // ---- phase 2: glh -> 2 fp16 planes (all 1024 threads; skip on last) ----
    if (!lastT) {
      int prow = tid & 31, kunit = tid >> 5;  // kunit 0..31
      const float* gsrc = glh + prow * GLHS + kunit * 8;
      float4 v0 = *(const float4*)(gsrc);
      float4 v1 = *(const float4*)(gsrc + 4);
      _Float16 m[8], r[8];
      split2h(v0.x, m[0], r[0]); split2h(v0.y, m[1], r[1]);
      split2h(v0.z, m[2], r[2]); split2h(v0.w, m[3], r[3]);
      split2h(v1.x, m[4], r[4]); split2h(v1.y, m[5], r[5]);
      split2h(v1.z, m[6], r[6]); split2h(v1.w, m[7], r[7]);
      int hks = kunit >> 1, kh = kunit & 1;
      char* basep = smem + (size_t)(hks * 4 + kh) * 512 + prow * 16;
      *(f16x8*)(basep) = *(f16x8*)m;
      *(f16x8*)(basep + 1024) = *(f16x8*)r;
    }
    // next iteration's B1 orders plane writes before k-loop reads
  }
#undef FRAG3
#undef XADDR
#undef HADDR
}

// ---------------- PRNG (threefry_partitionable=True semantics) ----------------
__global__ void k_prng_setup(uint32_t* sk) {
  uint32_t k0, k1, s0, s1, t0, t1;
  tf2x32(0u, 7u, 0u, 0u, k0, k1);
  tf2x32(0u, 7u, 0u, 1u, s0, s1);
  tf2x32(k0, k1, 0u, 1u, t0, t1);
  sk[0] = s0; sk[1] = s1;
  sk[2] = t0; sk[3] = t1;
}

__global__ void k_genkeys(const uint32_t* __restrict__ sk, int which,
                          uint32_t* __restrict__ keys) {
  int i = blockIdx.x * blockDim.x + threadIdx.x;
  if (i < BN) {
    uint32_t o0, o1;
    tf2x32(sk[which * 2], sk[which * 2 + 1], 0u, (uint32_t)i, o0, o1);
    keys[i] = o0 ^ o1;
  }
}

// stable rank sort, tiled: 512 blocks x 16 elements, 16 threads/element
#define RSE 16
__global__ __launch_bounds__(256) void k_ranksort(const uint32_t* __restrict__ keys,
                                                  const int* __restrict__ vin,
                                                  int* __restrict__ vout) {
  __shared__ uint32_t skey[BN];
  __shared__ int psum[RSE][17];
  const int tid = threadIdx.x;
  const int g = tid >> 4;
  const int l = tid & 15;
  const int gi = blockIdx.x * RSE + g;
  for (int i = tid; i < BN; i += 256) skey[i] = keys[i];
  __syncthreads();
  const uint32_t ki = skey[gi];
  int rank = 0;
#pragma unroll 8
  for (int j = l; j < BN; j += 16) {
    uint32_t kj = skey[j];
    rank += (kj < ki) || (kj == ki && j < gi);
  }
  psum[g][l] = rank;
  __syncthreads();
  if (l == 0) {
    int r = 0;
#pragma unroll
    for (int tt = 0; tt < 16; ++tt) r += psum[g][tt];
    vout[r] = vin ? vin[gi] : gi;
  }
}

// ---------------- k-means (decisions in f64) ----------------
__global__ void k_init_centers(const float* __restrict__ h, const int* __restrict__ vals2,
                               float* __restrict__ centers, double* __restrict__ cnorm) {
  const int c = blockIdx.x, d = threadIdx.x;
  const int src = vals2[c];
  float v = h[(size_t)src * HH + d];
  centers[c * HH + d] = v;
  __shared__ double red[HH];
  red[d] = (double)v * (double)v;
  __syncthreads();
  for (int s = 128; s > 0; s >>= 1) {
    if (d < s) red[d] += red[d + s];
    __syncthreads();
  }
  if (d == 0) cnorm[c] = red[0];
}

// 2 threads per row: each sums half of K, f64 shfl_xor combine, even lane decides.
__global__ __launch_bounds__(128) void k_assign(const float* __restrict__ h,
                                                const float* __restrict__ centers,
                                                const double* __restrict__ cnorm,
                                                int* __restrict__ codes) {
  __shared__ float sc[KK * HH];
  __shared__ double sn[KK];
  const int tid = threadIdx.x;
  for (int idx = tid; idx < KK * HH; idx += 128) sc[idx] = centers[idx];
  if (tid < KK) sn[tid] = cnorm[tid];
  __syncthreads();
  const int gid = blockIdx.x * 128 + tid;
  const int b = gid >> 1, half = gid & 1;
  const float4* hp = (const float4*)&h[(size_t)b * HH + half * 128];
  const float* sch = sc + half * 128;
  double acc[KK] = {};
  double xn = 0.0;
  for (int k4 = 0; k4 < 32; ++k4) {
    float4 xv = hp[k4];
    double x0 = xv.x, x1 = xv.y, x2 = xv.z, x3 = xv.w;
    xn += x0 * x0 + x1 * x1 + x2 * x2 + x3 * x3;
#pragma unroll
    for (int c = 0; c < KK; ++c) {
      float4 cv = *(const float4*)&sch[c * HH + k4 * 4];
      acc[c] += x0 * cv.x + x1 * cv.y + x2 * cv.z + x3 * cv.w;
    }
  }
  xn += __shfl_xor(xn, 1);
#pragma unroll
  for (int c = 0; c < KK; ++c) acc[c] += __shfl_xor(acc[c], 1);
  if (half == 0) {
    int best = 0;
    double bd = xn - 2.0 * acc[0] + sn[0];
#pragma unroll
    for (int c = 1; c < KK; ++c) {
      double d2 = xn - 2.0 * acc[c] + sn[c];
      if (d2 < bd) { bd = d2; best = c; }
    }
    codes[b] = best;
  }
}

__global__ __launch_bounds__(256) void k_upd_partial(const float* __restrict__ h,
                                                     const int* __restrict__ codes,
                                                     double* __restrict__ psum,
                                                     float* __restrict__ pcnt) {
  __shared__ double acc[KK * HH];
  __shared__ int lc[UPB];
  const int tid = threadIdx.x;
  for (int idx = tid; idx < KK * HH; idx += 256) acc[idx] = 0.0;
  const int p0 = blockIdx.x * UPB;
  for (int idx = tid; idx < UPB; idx += 256) lc[idx] = codes[p0 + idx];
  __syncthreads();
  const int d = tid;
  for (int p = 0; p < UPB; ++p) {
    int c = lc[p];
    acc[c * HH + d] += (double)h[(size_t)(p0 + p) * HH + d];
  }
  if (tid < KK) {
    float cnt = 0.f;
    for (int p = 0; p < UPB; ++p) cnt += (lc[p] == tid) ? 1.f : 0.f;
    pcnt[blockIdx.x * KK + tid] = cnt;
  }
  for (int c = 0; c < KK; ++c)
    psum[((size_t)blockIdx.x * KK + c) * HH + d] = acc[c * HH + d];
}

__global__ void k_upd_final(const double* __restrict__ psum, const float* __restrict__ pcnt,
                            float* __restrict__ centers, double* __restrict__ cnorm) {
  const int c = blockIdx.x, d = threadIdx.x;
  double s = 0.0;
  for (int b = 0; b < UB; ++b) s += psum[((size_t)b * KK + c) * HH + d];
  float cnt = 0.f;
  for (int b = 0; b < UB; ++b) cnt += pcnt[b * KK + c];
  if (cnt <= 0.5f) cnt = 1.f;
  float v = (float)(s / (double)cnt);
  centers[c * HH + d] = v;
  __shared__ double red[HH];
  red[d] = (double)v * (double)v;
  __syncthreads();
  for (int s2 = 128; s2 > 0; s2 >>= 1) {
    if (d < s2) red[d] += red[d + s2];
    __syncthreads();
  }
  if (d == 0) cnorm[c] = red[0];
}

// ---------------- gumbel hard assignment (f64 decisions) ----------------
__global__ __launch_bounds__(128) void k_gumbel(const float* __restrict__ h,
                                                const float* __restrict__ centers,
                                                int* __restrict__ codeg) {
  __shared__ float sc[KK * HH];
  const int tid = threadIdx.x;
  for (int idx = tid; idx < KK * HH; idx += 128) sc[idx] = centers[idx];
  __syncthreads();
  const int b = blockIdx.x * 128 + tid;
  const float4* hp = (const float4*)&h[(size_t)b * HH];
  double acc[KK] = {};
  for (int k4 = 0; k4 < HH / 4; ++k4) {
    float4 xv = hp[k4];
    double x0 = xv.x, x1 = xv.y, x2 = xv.z, x3 = xv.w;
#pragma unroll
    for (int c = 0; c < KK; ++c) {
      float4 cv = *(const float4*)&sc[c * HH + k4 * 4];
      acc[c] += x0 * cv.x + x1 * cv.y + x2 * cv.z + x3 * cv.w;
    }
  }
  int best = 0;
  double bv = -1e300;
#pragma unroll
  for (int c = 0; c < KK; ++c) {
    double e = acc[c] > 0.0 ? acc[c] : 0.0;
    uint32_t j = (uint32_t)(b * KK + c);
    uint32_t o0, o1;
    tf2x32(0u, 42u, 0u, j, o0, o1);
    double U = (double)bits_to_unit(o0 ^ o1);
    double g = -log(-log(U + 1e-20) + 1e-20);
    double v = e + g;
    if (v > bv) { bv = v; best = c; }
  }
  codeg[b] = best;
}

// ---------------- GCN layer (adj = I) ----------------
__global__ void k_gcn(const float* __restrict__ in, const float* __restrict__ w,
                      const float* __restrict__ bias, float* __restrict__ out) {
  const int c = blockIdx.x, d = threadIdx.x;
  __shared__ float si[HH];
  si[d] = in[c * HH + d];
  __syncthreads();
  float acc = 0.f;
  for (int k = 0; k < HH; ++k) acc += si[k] * w[k * HH + d];
  acc += bias[d];
  out[c * HH + d] = acc > 0.f ? acc : 0.f;
}

// ---------------- final blend (f32 output) ----------------
__global__ __launch_bounds__(256) void k_final(const float* __restrict__ h,
                                               const float* __restrict__ h2,
                                               const int* __restrict__ codeg,
                                               const float* __restrict__ w1,
                                               const float* __restrict__ w1b,
                                               const float* __restrict__ w2,
                                               const float* __restrict__ w2b,
                                               float* __restrict__ out) {
  const int b = blockIdx.x, d = threadIdx.x;
  const int cg = codeg[b];
  const float cd = h2[cg * HH + d];
  const float hd = h[(size_t)b * HH + d];
  __shared__ float r1[HH], r2[HH];
  __shared__ float wan_s;
  r1[d] = cd * w1[d];
  r2[d] = hd * w2[d];
  __syncthreads();
  for (int s = 128; s > 0; s >>= 1) {
    if (d < s) { r1[d] += r1[d + s]; r2[d] += r2[d + s]; }
    __syncthreads();
  }
  if (d == 0) {
    float wa = 1.f / (1.f + expf(-(r1[0] + w1b[0])));
    float wb = 1.f / (1.f + expf(-(r2[0] + w2b[0])));
    wan_s = wa / (wa + wb);
  }
  __syncthreads();
  float wan = wan_s;
  out[(size_t)b * HH + d] = wan * cd + (1.f - wan) * hd;
}

// ---------------- launch ----------------
extern "C" void kernel_launch(void* const* d_in, const int* in_sizes, int n_in,
                              void* d_out, int out_size, void* d_ws, size_t ws_size,
                              hipStream_t stream) {
  const float* x   = (const float*)d_in[0];
  const float* wih = (const float*)d_in[1];
  const float* whh = (const float*)d_in[2];
  const float* bih = (const float*)d_in[3];
  const float* bhh = (const float*)d_in[4];
  const float* g1w = (const float*)d_in[5];
  const float* g1b = (const float*)d_in[6];
  const float* g2w = (const float*)d_in[7];
  const float* g2b = (const float*)d_in[8];
  const float* w1w = (const float*)d_in[9];
  const float* w1b = (const float*)d_in[10];
  const float* w2w = (const float*)d_in[11];
  const float* w2b = (const float*)d_in[12];
  float* out = (float*)d_out;

  char* wsb = (char*)d_ws;
  size_t off = 0;
  auto alloc = [&](size_t bytes) {
    void* p = wsb + off;
    off += (bytes + 255) & ~(size_t)255;
    return p;
  };
  float* hf0      = (float*)alloc((size_t)BN * HH * 4);
  char*  wpk4     = (char*)alloc((size_t)KSTEPS * 24 * 2 * 64 * 16);
  float* centers  = (float*)alloc(KK * HH * 4);
  double* cnorm   = (double*)alloc(KK * 8);
  int*   codes    = (int*)alloc(BN * 4);
  int*   codeg    = (int*)alloc(BN * 4);
  uint32_t* keys  = (uint32_t*)alloc(BN * 4);
  int*   vals1    = (int*)alloc(BN * 4);
  int*   vals2    = (int*)alloc(BN * 4);
  uint32_t* sk    = (uint32_t*)alloc(4 * 4);
  double* psum    = (double*)alloc((size_t)UB * KK * HH * 8);
  float* pcnt     = (float*)alloc(UB * KK * 4);
  float* hh1      = (float*)alloc(KK * HH * 4);
  float* hh2      = (float*)alloc(KK * HH * 4);

  k_pack4<<<(KSTEPS * 24 * 2 * 64 + 255) / 256, 256, 0, stream>>>(wih, whh, wpk4);
  k_gru_v9<<<BN / 32, 1024, 0, stream>>>(x, wpk4, bih, bhh, hf0);
  float* h = hf0;

  k_prng_setup<<<1, 1, 0, stream>>>(sk);
  k_genkeys<<<32, 256, 0, stream>>>(sk, 0, keys);
  k_ranksort<<<BN / RSE, 256, 0, stream>>>(keys, (const int*)nullptr, vals1);
  k_genkeys<<<32, 256, 0, stream>>>(sk, 1, keys);
  k_ranksort<<<BN / RSE, 256, 0, stream>>>(keys, vals1, vals2);

  k_init_centers<<<KK, HH, 0, stream>>>(h, vals2, centers, cnorm);
  k_assign<<<BN * 2 / 128, 128, 0, stream>>>(h, centers, cnorm, codes);
  for (int it = 0; it < KM_ITERS_N; ++it) {
    k_upd_partial<<<UB, 256, 0, stream>>>(h, codes, psum, pcnt);
    k_upd_final<<<KK, HH, 0, stream>>>(psum, pcnt, centers, cnorm);
    k_assign<<<BN * 2 / 128, 128, 0, stream>>>(h, centers, cnorm, codes);
  }
  k_upd_partial<<<UB, 256, 0, stream>>>(h, codes, psum, pcnt);
  k_upd_final<<<KK, HH, 0, stream>>>(psum, pcnt, centers, cnorm);

  k_gumbel<<<BN / 128, 128, 0, stream>>>(h, centers, codeg);
  k_gcn<<<KK, HH, 0, stream>>>(centers, g1w, g1b, hh1);
  k_gcn<<<KK, HH, 0, stream>>>(hh1, g2w, g2b, hh2);
  k_final<<<BN, HH, 0, stream>>>(h, hh2, codeg, w1w, w1b, w2w, w2b, out);
}

// Round 18
// 3820.174 us; speedup vs baseline: 2.1944x; 2.1944x over previous
//
#include <hip/hip_runtime.h>
#include <hip/hip_bf16.h>
#include <stdint.h>

#define BN 8192
#define TT 128
#define II 64
#define HH 256
#define GG 768
#define KK 12
#define KM_ITERS_N 25
#define KSTEPS 20
#define FAB 32
#define NPART (BN/FAB)

typedef __attribute__((ext_vector_type(8))) _Float16 f16x8;
typedef __attribute__((ext_vector_type(4))) _Float16 f16x4;
typedef __attribute__((ext_vector_type(16))) float f32x16;

// ---------------- threefry2x32 (JAX-exact) ----------------
__device__ __forceinline__ uint32_t rotl32(uint32_t v, int d) {
  return (v << d) | (v >> (32 - d));
}
__device__ __forceinline__ void tf2x32(uint32_t k0, uint32_t k1,
                                       uint32_t x0, uint32_t x1,
                                       uint32_t& o0, uint32_t& o1) {
  uint32_t ks2 = k0 ^ k1 ^ 0x1BD11BDAu;
  x0 += k0; x1 += k1;
#define TFR(r) { x0 += x1; x1 = rotl32(x1, r); x1 ^= x0; }
  TFR(13); TFR(15); TFR(26); TFR(6);   x0 += k1;  x1 += ks2 + 1u;
  TFR(17); TFR(29); TFR(16); TFR(24);  x0 += ks2; x1 += k0 + 2u;
  TFR(13); TFR(15); TFR(26); TFR(6);   x0 += k0;  x1 += k1 + 3u;
  TFR(17); TFR(29); TFR(16); TFR(24);  x0 += k1;  x1 += ks2 + 4u;
  TFR(13); TFR(15); TFR(26); TFR(6);   x0 += ks2; x1 += k0 + 5u;
#undef TFR
  o0 = x0; o1 = x1;
}
__device__ __forceinline__ float bits_to_unit(uint32_t bits) {
  uint32_t u = (bits >> 9) | 0x3f800000u;
  return __uint_as_float(u) - 1.0f;
}

// ---------------- fp16 2-plane split (residual scaled by 4096) ----------------
#define RSCL 4096.f
#define RINV (1.f / 4096.f)
__device__ __forceinline__ void split2h(float v, _Float16& m, _Float16& r) {
  m = (_Float16)v;
  r = (_Float16)((v - (float)m) * RSCL);
}

// ---------------- fast gates (exp2-based; v_exp_f32 native) ----------------
__device__ __forceinline__ float sigm_f(float u) {
  return 1.f / (1.f + exp2f(u * -1.4426950408889634f));
}
__device__ __forceinline__ float tanh_f(float u) {
  return 1.f - 2.f / (1.f + exp2f(u * 2.8853900817779268f));
}

// ---------------- weight pack: [ks 20][cf 24][p 2][lane 64]*16B ----------------
__global__ void k_pack4(const float* __restrict__ wih, const float* __restrict__ whh,
                        char* __restrict__ wpk4) {
  int u = blockIdx.x * 256 + threadIdx.x;
  if (u >= KSTEPS * 24 * 2 * 64) return;
  int lane = u & 63; int rest = u >> 6;
  int p = rest & 1; rest >>= 1;
  int cf = rest % 24; int ks = rest / 24;
  int l31 = lane & 31, khalf = lane >> 5;
  int col = cf * 32 + l31;
  int gate = col >> 8, d = col & 255;
  int grow = gate * 256 + d;
  _Float16 s[8];
#pragma unroll
  for (int j = 0; j < 8; ++j) {
    int k = khalf * 8 + j;
    float wv = (ks < 4) ? wih[grow * II + ks * 16 + k]
                        : whh[grow * HH + (ks - 4) * 16 + k];
    _Float16 m, r;
    split2h(wv, m, r);
    s[j] = p ? r : m;
  }
  *(f16x8*)(wpk4 + (size_t)u * 16) = *(f16x8*)s;
}

// ---------------- persistent MFMA GRU v8 (fp16 2-plane, two-pass) — round-16 verified ----------------
#define GLHS 260
#define GLB 40960

__global__ __launch_bounds__(512, 2) void k_gru_v8(
    const float* __restrict__ x, const char* __restrict__ wpk4,
    const float* __restrict__ bih, const float* __restrict__ bhh,
    float* __restrict__ hf_out) {
  __shared__ __align__(16) char smem[74240];
  float* glh = (float*)(smem + GLB);
  const int tid = threadIdx.x;
  const int w = tid >> 6;
  const int l = tid & 63, l31 = l & 31, kh5 = l >> 5;
  const int row0 = blockIdx.x * 32;

  {  // zero h planes (32 KB) + glh
    int4 z = {0, 0, 0, 0};
    int4* s4 = (int4*)smem;
#pragma unroll
    for (int i = 0; i < 4; ++i) s4[tid + i * 512] = z;
    for (int i = tid; i < 32 * GLHS; i += 512) glh[i] = 0.f;
  }
  const int d = w * 32 + l31;
  const float biR = bih[d],          bhR = bhh[d];
  const float biZ = bih[HH + d],     bhZ = bhh[HH + d];
  const float biN = bih[2 * HH + d], bhN = bhh[2 * HH + d];

  const int xrow = tid & 31, xko4 = tid >> 5;
  const float* xbase = x + (size_t)(row0 + xrow) * (TT * II) + xko4 * 4;
  float4 xreg = *(const float4*)xbase;
  __syncthreads();

#define FRAG3(ACCM, ACCR, CF, KS)                                                  \
    {                                                                              \
      const char* bf = wpk4 + (((size_t)(KS) * 24 + (CF)) * 2) * 1024 +            \
                       (size_t)l * 16;                                             \
      f16x8 b0 = *(const f16x8*)(bf);                                              \
      f16x8 b1 = *(const f16x8*)(bf + 1024);                                       \
      ACCM = __builtin_amdgcn_mfma_f32_32x32x16_f16(a0, b0, ACCM, 0, 0, 0);        \
      ACCR = __builtin_amdgcn_mfma_f32_32x32x16_f16(a0, b1, ACCR, 0, 0, 0);        \
      ACCR = __builtin_amdgcn_mfma_f32_32x32x16_f16(a1, b0, ACCR, 0, 0, 0);        \
    }

  for (int t = 0; t < TT; ++t) {
    {
      _Float16 m[4], r[4];
      split2h(xreg.x, m[0], r[0]);
      split2h(xreg.y, m[1], r[1]);
      split2h(xreg.z, m[2], r[2]);
      split2h(xreg.w, m[3], r[3]);
      int xks = xko4 >> 2, kh = (xko4 >> 1) & 1, sub = (xko4 & 1) * 8;
      char* b0 = smem + 32768 + (size_t)(xks * 4 + kh) * 512 + xrow * 16 + sub;
      *(f16x4*)b0 = *(f16x4*)m;
      *(f16x4*)(b0 + 1024) = *(f16x4*)r;
    }
    if (t + 1 < TT) xreg = *(const float4*)(xbase + (size_t)(t + 1) * II);
    __syncthreads();

    f32x16 rrv, zzv;
    {
      f32x16 aRm = (f32x16)0.f, aRr = (f32x16)0.f;
      f32x16 aZm = (f32x16)0.f, aZr = (f32x16)0.f;
#pragma unroll
      for (int ks = 0; ks < 4; ++ks) {
        const char* ab = smem + 32768 + (size_t)(ks * 4 + kh5) * 512 + l31 * 16;
        f16x8 a0 = *(const f16x8*)(ab);
        f16x8 a1 = *(const f16x8*)(ab + 1024);
        FRAG3(aRm, aRr, w, ks) FRAG3(aZm, aZr, 8 + w, ks)
      }
#pragma unroll 4
      for (int ks = 4; ks < KSTEPS; ++ks) {
        const char* ab = smem + (size_t)((ks - 4) * 4 + kh5) * 512 + l31 * 16;
        f16x8 a0 = *(const f16x8*)(ab);
        f16x8 a1 = *(const f16x8*)(ab + 1024);
        FRAG3(aRm, aRr, w, ks) FRAG3(aZm, aZr, 8 + w, ks)
      }
#pragma unroll
      for (int j = 0; j < 16; ++j) {
        rrv[j] = sigm_f(aRm[j] + aRr[j] * RINV + biR + bhR);
        zzv[j] = sigm_f(aZm[j] + aZr[j] * RINV + biZ + bhZ);
      }
    }
    f32x16 aNxm = (f32x16)0.f, aNxr = (f32x16)0.f;
    f32x16 aNhm = (f32x16)0.f, aNhr = (f32x16)0.f;
#pragma unroll
    for (int ks = 0; ks < 4; ++ks) {
      const char* ab = smem + 32768 + (size_t)(ks * 4 + kh5) * 512 + l31 * 16;
      f16x8 a0 = *(const f16x8*)(ab);
      f16x8 a1 = *(const f16x8*)(ab + 1024);
      FRAG3(aNxm, aNxr, 16 + w, ks)
    }
#pragma unroll 4
    for (int ks = 4; ks < KSTEPS; ++ks) {
      const char* ab = smem + (size_t)((ks - 4) * 4 + kh5) * 512 + l31 * 16;
      f16x8 a0 = *(const f16x8*)(ab);
      f16x8 a1 = *(const f16x8*)(ab + 1024);
      FRAG3(aNhm, aNhr, 16 + w, ks)
    }
    __syncthreads();

    const bool lastT = (t == TT - 1);
#pragma unroll
    for (int j = 0; j < 16; ++j) {
      int row = (j & 3) + ((j >> 2) << 3) + kh5 * 4;
      float hold = glh[row * GLHS + d];
      float Nx = aNxm[j] + aNxr[j] * RINV;
      float Nh = aNhm[j] + aNhr[j] * RINV;
      float nn = tanh_f(Nx + biN + rrv[j] * (Nh + bhN));
      float hnew = (1.f - zzv[j]) * nn + zzv[j] * hold;
      glh[row * GLHS + d] = hnew;
      if (lastT) hf_out[(size_t)(row0 + row) * HH + d] = hnew;
    }
    __syncthreads();

    if (!lastT) {
#pragma unroll
      for (int i = 0; i < 2; ++i) {
        int u = tid + i * 512;
        int prow = u & 31, kunit = u >> 5;
        const float* gsrc = glh + prow * GLHS + kunit * 8;
        float4 v0 = *(const float4*)(gsrc);
        float4 v1 = *(const float4*)(gsrc + 4);
        _Float16 m[8], r[8];
        split2h(v0.x, m[0], r[0]); split2h(v0.y, m[1], r[1]);
        split2h(v0.z, m[2], r[2]); split2h(v0.w, m[3], r[3]);
        split2h(v1.x, m[4], r[4]); split2h(v1.y, m[5], r[5]);
        split2h(v1.z, m[6], r[6]); split2h(v1.w, m[7], r[7]);
        int hks = kunit >> 1, kh = kunit & 1;
        char* basep = smem + (size_t)(hks * 4 + kh) * 512 + prow * 16;
        *(f16x8*)(basep) = *(f16x8*)m;
        *(f16x8*)(basep + 1024) = *(f16x8*)r;
      }
    }
  }
#undef FRAG3
}

// ---------------- PRNG (threefry_partitionable=True semantics) ----------------
__global__ void k_prng_setup(uint32_t* sk) {
  uint32_t k0, k1, s0, s1, t0, t1;
  tf2x32(0u, 7u, 0u, 0u, k0, k1);
  tf2x32(0u, 7u, 0u, 1u, s0, s1);
  tf2x32(k0, k1, 0u, 1u, t0, t1);
  sk[0] = s0; sk[1] = s1;
  sk[2] = t0; sk[3] = t1;
}

__global__ void k_genkeys(const uint32_t* __restrict__ sk, int which,
                          uint32_t* __restrict__ keys) {
  int i = blockIdx.x * blockDim.x + threadIdx.x;
  if (i < BN) {
    uint32_t o0, o1;
    tf2x32(sk[which * 2], sk[which * 2 + 1], 0u, (uint32_t)i, o0, o1);
    keys[i] = o0 ^ o1;
  }
}

// stable rank sort, tiled: 512 blocks x 16 elements, 16 threads/element
#define RSE 16
__global__ __launch_bounds__(256) void k_ranksort(const uint32_t* __restrict__ keys,
                                                  const int* __restrict__ vin,
                                                  int* __restrict__ vout) {
  __shared__ uint32_t skey[BN];
  __shared__ int psum[RSE][17];
  const int tid = threadIdx.x;
  const int g = tid >> 4;
  const int l = tid & 15;
  const int gi = blockIdx.x * RSE + g;
  for (int i = tid; i < BN; i += 256) skey[i] = keys[i];
  __syncthreads();
  const uint32_t ki = skey[gi];
  int rank = 0;
#pragma unroll 8
  for (int j = l; j < BN; j += 16) {
    uint32_t kj = skey[j];
    rank += (kj < ki) || (kj == ki && j < gi);
  }
  psum[g][l] = rank;
  __syncthreads();
  if (l == 0) {
    int r = 0;
#pragma unroll
    for (int tt = 0; tt < 16; ++tt) r += psum[g][tt];
    vout[r] = vin ? vin[gi] : gi;
  }
}

// ---------------- k-means ----------------
__global__ void k_init_centers(const float* __restrict__ h, const int* __restrict__ vals2,
                               float* __restrict__ centers, double* __restrict__ cnorm) {
  const int c = blockIdx.x, d = threadIdx.x;
  const int src = vals2[c];
  float v = h[(size_t)src * HH + d];
  centers[c * HH + d] = v;
  __shared__ double red[HH];
  red[d] = (double)v * (double)v;
  __syncthreads();
  for (int s = 128; s > 0; s >>= 1) {
    if (d < s) red[d] += red[d + s];
    __syncthreads();
  }
  if (d == 0) cnorm[c] = red[0];
}

// fused assign + partial-update: 256 blocks x 256 thr, 32 rows/block.
// 8 threads/row (32-d segments), f64 dots + shfl_xor tree combine, argmin by seg 0;
// then per-column f64 accumulation of the block's 32 rows (same scheme as before).
__global__ __launch_bounds__(256) void k_fa(const float* __restrict__ h,
                                            const float* __restrict__ centers,
                                            const double* __restrict__ cnorm,
                                            double* __restrict__ psum,
                                            float* __restrict__ pcnt) {
  __shared__ float sc[KK * HH];
  __shared__ double sn[KK];
  __shared__ int lcode[FAB];
  __shared__ double acc[KK * HH];   // 24 KB
  const int tid = threadIdx.x;
  for (int i = tid; i < KK * HH; i += 256) { sc[i] = centers[i]; acc[i] = 0.0; }
  if (tid < KK) sn[tid] = cnorm[tid];
  __syncthreads();
  const int row0 = blockIdx.x * FAB;
  const int r = tid >> 3, seg = tid & 7;
  const int grow = row0 + r;
  const float4* hp = (const float4*)&h[(size_t)grow * HH + seg * 32];
  const float* schp = sc + seg * 32;
  double dot[KK] = {};
  double xn = 0.0;
#pragma unroll
  for (int k4 = 0; k4 < 8; ++k4) {
    float4 xv = hp[k4];
    double x0 = xv.x, x1 = xv.y, x2 = xv.z, x3 = xv.w;
    xn += x0 * x0 + x1 * x1 + x2 * x2 + x3 * x3;
#pragma unroll
    for (int c = 0; c < KK; ++c) {
      float4 cv = *(const float4*)&schp[c * HH + k4 * 4];
      dot[c] += x0 * cv.x + x1 * cv.y + x2 * cv.z + x3 * cv.w;
    }
  }
  xn += __shfl_xor(xn, 1); xn += __shfl_xor(xn, 2); xn += __shfl_xor(xn, 4);
#pragma unroll
  for (int c = 0; c < KK; ++c) {
    dot[c] += __shfl_xor(dot[c], 1);
    dot[c] += __shfl_xor(dot[c], 2);
    dot[c] += __shfl_xor(dot[c], 4);
  }
  if (seg == 0) {
    int best = 0;
    double bd = xn - 2.0 * dot[0] + sn[0];
#pragma unroll
    for (int c = 1; c < KK; ++c) {
      double d2 = xn - 2.0 * dot[c] + sn[c];
      if (d2 < bd) { bd = d2; best = c; }
    }
    lcode[r] = best;
  }
  __syncthreads();
  const int d = tid;   // column owner -> deterministic order
  for (int p = 0; p < FAB; ++p)
    acc[lcode[p] * HH + d] += (double)h[(size_t)(row0 + p) * HH + d];
  if (tid < KK) {
    float cnt = 0.f;
    for (int p = 0; p < FAB; ++p) cnt += (lcode[p] == tid) ? 1.f : 0.f;
    pcnt[blockIdx.x * KK + tid] = cnt;
  }
  for (int c = 0; c < KK; ++c)
    psum[((size_t)blockIdx.x * KK + c) * HH + d] = acc[c * HH + d];
}

__global__ void k_upd_final(const double* __restrict__ psum, const float* __restrict__ pcnt,
                            float* __restrict__ centers, double* __restrict__ cnorm) {
  const int c = blockIdx.x, d = threadIdx.x;
  double s = 0.0;
  for (int b = 0; b < NPART; ++b) s += psum[((size_t)b * KK + c) * HH + d];
  float cnt = 0.f;
  for (int b = 0; b < NPART; ++b) cnt += pcnt[b * KK + c];
  if (cnt <= 0.5f) cnt = 1.f;
  float v = (float)(s / (double)cnt);
  centers[c * HH + d] = v;
  __shared__ double red[HH];
  red[d] = (double)v * (double)v;
  __syncthreads();
  for (int s2 = 128; s2 > 0; s2 >>= 1) {
    if (d < s2) red[d] += red[d + s2];
    __syncthreads();
  }
  if (d == 0) cnorm[c] = red[0];
}

// ---------------- gumbel hard assignment (f64 decisions) ----------------
__global__ __launch_bounds__(128) void k_gumbel(const float* __restrict__ h,
                                                const float* __restrict__ centers,
                                                int* __restrict__ codeg) {
  __shared__ float sc[KK * HH];
  const int tid = threadIdx.x;
  for (int idx = tid; idx < KK * HH; idx += 128) sc[idx] = centers[idx];
  __syncthreads();
  const int b = blockIdx.x * 128 + tid;
  const float4* hp = (const float4*)&h[(size_t)b * HH];
  double acc[KK] = {};
  for (int k4 = 0; k4 < HH / 4; ++k4) {
    float4 xv = hp[k4];
    double x0 = xv.x, x1 = xv.y, x2 = xv.z, x3 = xv.w;
#pragma unroll
    for (int c = 0; c < KK; ++c) {
      float4 cv = *(const float4*)&sc[c * HH + k4 * 4];
      acc[c] += x0 * cv.x + x1 * cv.y + x2 * cv.z + x3 * cv.w;
    }
  }
  int best = 0;
  double bv = -1e300;
#pragma unroll
  for (int c = 0; c < KK; ++c) {
    double e = acc[c] > 0.0 ? acc[c] : 0.0;
    uint32_t j = (uint32_t)(b * KK + c);
    uint32_t o0, o1;
    tf2x32(0u, 42u, 0u, j, o0, o1);
    double U = (double)bits_to_unit(o0 ^ o1);
    double g = -log(-log(U + 1e-20) + 1e-20);
    double v = e + g;
    if (v > bv) { bv = v; best = c; }
  }
  codeg[b] = best;
}

// ---------------- GCN layer (adj = I) ----------------
__global__ void k_gcn(const float* __restrict__ in, const float* __restrict__ w,
                      const float* __restrict__ bias, float* __restrict__ out) {
  const int c = blockIdx.x, d = threadIdx.x;
  __shared__ float si[HH];
  si[d] = in[c * HH + d];
  __syncthreads();
  float acc = 0.f;
  for (int k = 0; k < HH; ++k) acc += si[k] * w[k * HH + d];
  acc += bias[d];
  out[c * HH + d] = acc > 0.f ? acc : 0.f;
}

// ---------------- final blend (f32 output) ----------------
__global__ __launch_bounds__(256) void k_final(const float* __restrict__ h,
                                               const float* __restrict__ h2,
                                               const int* __restrict__ codeg,
                                               const float* __restrict__ w1,
                                               const float* __restrict__ w1b,
                                               const float* __restrict__ w2,
                                               const float* __restrict__ w2b,
                                               float* __restrict__ out) {
  const int b = blockIdx.x, d = threadIdx.x;
  const int cg = codeg[b];
  const float cd = h2[cg * HH + d];
  const float hd = h[(size_t)b * HH + d];
  __shared__ float r1[HH], r2[HH];
  __shared__ float wan_s;
  r1[d] = cd * w1[d];
  r2[d] = hd * w2[d];
  __syncthreads();
  for (int s = 128; s > 0; s >>= 1) {
    if (d < s) { r1[d] += r1[d + s]; r2[d] += r2[d + s]; }
    __syncthreads();
  }
  if (d == 0) {
    float wa = 1.f / (1.f + expf(-(r1[0] + w1b[0])));
    float wb = 1.f / (1.f + expf(-(r2[0] + w2b[0])));
    wan_s = wa / (wa + wb);
  }
  __syncthreads();
  float wan = wan_s;
  out[(size_t)b * HH + d] = wan * cd + (1.f - wan) * hd;
}

// ---------------- launch ----------------
extern "C" void kernel_launch(void* const* d_in, const int* in_sizes, int n_in,
                              void* d_out, int out_size, void* d_ws, size_t ws_size,
                              hipStream_t stream) {
  const float* x   = (const float*)d_in[0];
  const float* wih = (const float*)d_in[1];
  const float* whh = (const float*)d_in[2];
  const float* bih = (const float*)d_in[3];
  const float* bhh = (const float*)d_in[4];
  const float* g1w = (const float*)d_in[5];
  const float* g1b = (const float*)d_in[6];
  const float* g2w = (const float*)d_in[7];
  const float* g2b = (const float*)d_in[8];
  const float* w1w = (const float*)d_in[9];
  const float* w1b = (const float*)d_in[10];
  const float* w2w = (const float*)d_in[11];
  const float* w2b = (const float*)d_in[12];
  float* out = (float*)d_out;

  char* wsb = (char*)d_ws;
  size_t off = 0;
  auto alloc = [&](size_t bytes) {
    void* p = wsb + off;
    off += (bytes + 255) & ~(size_t)255;
    return p;
  };
  float* hf0      = (float*)alloc((size_t)BN * HH * 4);
  char*  wpk4     = (char*)alloc((size_t)KSTEPS * 24 * 2 * 64 * 16);
  float* centers  = (float*)alloc(KK * HH * 4);
  double* cnorm   = (double*)alloc(KK * 8);
  int*   codeg    = (int*)alloc(BN * 4);
  uint32_t* keys  = (uint32_t*)alloc(BN * 4);
  int*   vals1    = (int*)alloc(BN * 4);
  int*   vals2    = (int*)alloc(BN * 4);
  uint32_t* sk    = (uint32_t*)alloc(4 * 4);
  double* psum    = (double*)alloc((size_t)NPART * KK * HH * 8);
  float* pcnt     = (float*)alloc(NPART * KK * 4);
  float* hh1      = (float*)alloc(KK * HH * 4);
  float* hh2      = (float*)alloc(KK * HH * 4);

  k_pack4<<<(KSTEPS * 24 * 2 * 64 + 255) / 256, 256, 0, stream>>>(wih, whh, wpk4);
  k_gru_v8<<<BN / 32, 512, 0, stream>>>(x, wpk4, bih, bhh, hf0);
  float* h = hf0;

  k_prng_setup<<<1, 1, 0, stream>>>(sk);
  k_genkeys<<<32, 256, 0, stream>>>(sk, 0, keys);
  k_ranksort<<<BN / RSE, 256, 0, stream>>>(keys, (const int*)nullptr, vals1);
  k_genkeys<<<32, 256, 0, stream>>>(sk, 1, keys);
  k_ranksort<<<BN / RSE, 256, 0, stream>>>(keys, vals1, vals2);

  k_init_centers<<<KK, HH, 0, stream>>>(h, vals2, centers, cnorm);
  k_fa<<<NPART, 256, 0, stream>>>(h, centers, cnorm, psum, pcnt);
  for (int it = 0; it < KM_ITERS_N; ++it) {
    k_upd_final<<<KK, HH, 0, stream>>>(psum, pcnt, centers, cnorm);
    k_fa<<<NPART, 256, 0, stream>>>(h, centers, cnorm, psum, pcnt);
  }
  k_upd_final<<<KK, HH, 0, stream>>>(psum, pcnt, centers, cnorm);

  k_gumbel<<<BN / 128, 128, 0, stream>>>(h, centers, codeg);
  k_gcn<<<KK, HH, 0, stream>>>(centers, g1w, g1b, hh1);
  k_gcn<<<KK, HH, 0, stream>>>(hh1, g2w, g2b, hh2);
  k_final<<<BN, HH, 0, stream>>>(h, hh2, codeg, w1w, w1b, w2w, w2b, out);
}

// Round 19
// 3372.078 us; speedup vs baseline: 2.4860x; 1.1329x over previous
//
#include <hip/hip_runtime.h>
#include <hip/hip_bf16.h>
#include <stdint.h>

#define BN 8192
#define TT 128
#define II 64
#define HH 256
#define GG 768
#define KK 12
#define KM_ITERS_N 25
#define KSTEPS 20
#define FAB 32
#define NPART (BN/FAB)

typedef __attribute__((ext_vector_type(8))) _Float16 f16x8;
typedef __attribute__((ext_vector_type(4))) _Float16 f16x4;
typedef __attribute__((ext_vector_type(16))) float f32x16;

// ---------------- threefry2x32 (JAX-exact) ----------------
__device__ __forceinline__ uint32_t rotl32(uint32_t v, int d) {
  return (v << d) | (v >> (32 - d));
}
__device__ __forceinline__ void tf2x32(uint32_t k0, uint32_t k1,
                                       uint32_t x0, uint32_t x1,
                                       uint32_t& o0, uint32_t& o1) {
  uint32_t ks2 = k0 ^ k1 ^ 0x1BD11BDAu;
  x0 += k0; x1 += k1;
#define TFR(r) { x0 += x1; x1 = rotl32(x1, r); x1 ^= x0; }
  TFR(13); TFR(15); TFR(26); TFR(6);   x0 += k1;  x1 += ks2 + 1u;
  TFR(17); TFR(29); TFR(16); TFR(24);  x0 += ks2; x1 += k0 + 2u;
  TFR(13); TFR(15); TFR(26); TFR(6);   x0 += k0;  x1 += k1 + 3u;
  TFR(17); TFR(29); TFR(16); TFR(24);  x0 += k1;  x1 += ks2 + 4u;
  TFR(13); TFR(15); TFR(26); TFR(6);   x0 += ks2; x1 += k0 + 5u;
#undef TFR
  o0 = x0; o1 = x1;
}
__device__ __forceinline__ float bits_to_unit(uint32_t bits) {
  uint32_t u = (bits >> 9) | 0x3f800000u;
  return __uint_as_float(u) - 1.0f;
}

// ---------------- fp16 2-plane split (residual scaled by 4096) ----------------
#define RSCL 4096.f
#define RINV (1.f / 4096.f)
__device__ __forceinline__ void split2h(float v, _Float16& m, _Float16& r) {
  m = (_Float16)v;
  r = (_Float16)((v - (float)m) * RSCL);
}

// ---------------- fast gates (exp2-based; v_exp_f32 native) ----------------
__device__ __forceinline__ float sigm_f(float u) {
  return 1.f / (1.f + exp2f(u * -1.4426950408889634f));
}
__device__ __forceinline__ float tanh_f(float u) {
  return 1.f - 2.f / (1.f + exp2f(u * 2.8853900817779268f));
}

// ---------------- weight pack: [ks 20][cf 24][p 2][lane 64]*16B ----------------
__global__ void k_pack4(const float* __restrict__ wih, const float* __restrict__ whh,
                        char* __restrict__ wpk4) {
  int u = blockIdx.x * 256 + threadIdx.x;
  if (u >= KSTEPS * 24 * 2 * 64) return;
  int lane = u & 63; int rest = u >> 6;
  int p = rest & 1; rest >>= 1;
  int cf = rest % 24; int ks = rest / 24;
  int l31 = lane & 31, khalf = lane >> 5;
  int col = cf * 32 + l31;
  int gate = col >> 8, d = col & 255;
  int grow = gate * 256 + d;
  _Float16 s[8];
#pragma unroll
  for (int j = 0; j < 8; ++j) {
    int k = khalf * 8 + j;
    float wv = (ks < 4) ? wih[grow * II + ks * 16 + k]
                        : whh[grow * HH + (ks - 4) * 16 + k];
    _Float16 m, r;
    split2h(wv, m, r);
    s[j] = p ? r : m;
  }
  *(f16x8*)(wpk4 + (size_t)u * 16) = *(f16x8*)s;
}

// ---------------- persistent MFMA GRU v8 (fp16 2-plane, two-pass) ----------------
#define GLHS 260
#define GLB 40960

__global__ __launch_bounds__(512, 2) void k_gru_v8(
    const float* __restrict__ x, const char* __restrict__ wpk4,
    const float* __restrict__ bih, const float* __restrict__ bhh,
    float* __restrict__ hf_out) {
  __shared__ __align__(16) char smem[74240];
  float* glh = (float*)(smem + GLB);
  const int tid = threadIdx.x;
  const int w = tid >> 6;
  const int l = tid & 63, l31 = l & 31, kh5 = l >> 5;
  const int row0 = blockIdx.x * 32;

  {  // zero h planes (32 KB) + glh
    int4 z = {0, 0, 0, 0};
    int4* s4 = (int4*)smem;
#pragma unroll
    for (int i = 0; i < 4; ++i) s4[tid + i * 512] = z;
    for (int i = tid; i < 32 * GLHS; i += 512) glh[i] = 0.f;
  }
  const int d = w * 32 + l31;
  const float biR = bih[d],          bhR = bhh[d];
  const float biZ = bih[HH + d],     bhZ = bhh[HH + d];
  const float biN = bih[2 * HH + d], bhN = bhh[2 * HH + d];

  const int xrow = tid & 31, xko4 = tid >> 5;
  const float* xbase = x + (size_t)(row0 + xrow) * (TT * II) + xko4 * 4;
  float4 xreg = *(const float4*)xbase;
  __syncthreads();

#define FRAG3(ACCM, ACCR, CF, KS)                                                  \
    {                                                                              \
      const char* bf = wpk4 + (((size_t)(KS) * 24 + (CF)) * 2) * 1024 +            \
                       (size_t)l * 16;                                             \
      f16x8 b0 = *(const f16x8*)(bf);                                              \
      f16x8 b1 = *(const f16x8*)(bf + 1024);                                       \
      ACCM = __builtin_amdgcn_mfma_f32_32x32x16_f16(a0, b0, ACCM, 0, 0, 0);        \
      ACCR = __builtin_amdgcn_mfma_f32_32x32x16_f16(a0, b1, ACCR, 0, 0, 0);        \
      ACCR = __builtin_amdgcn_mfma_f32_32x32x16_f16(a1, b0, ACCR, 0, 0, 0);        \
    }

  for (int t = 0; t < TT; ++t) {
    {
      _Float16 m[4], r[4];
      split2h(xreg.x, m[0], r[0]);
      split2h(xreg.y, m[1], r[1]);
      split2h(xreg.z, m[2], r[2]);
      split2h(xreg.w, m[3], r[3]);
      int xks = xko4 >> 2, kh = (xko4 >> 1) & 1, sub = (xko4 & 1) * 8;
      char* b0 = smem + 32768 + (size_t)(xks * 4 + kh) * 512 + xrow * 16 + sub;
      *(f16x4*)b0 = *(f16x4*)m;
      *(f16x4*)(b0 + 1024) = *(f16x4*)r;
    }
    if (t + 1 < TT) xreg = *(const float4*)(xbase + (size_t)(t + 1) * II);
    __syncthreads();

    f32x16 rrv, zzv;
    {
      f32x16 aRm = (f32x16)0.f, aRr = (f32x16)0.f;
      f32x16 aZm = (f32x16)0.f, aZr = (f32x16)0.f;
#pragma unroll
      for (int ks = 0; ks < 4; ++ks) {
        const char* ab = smem + 32768 + (size_t)(ks * 4 + kh5) * 512 + l31 * 16;
        f16x8 a0 = *(const f16x8*)(ab);
        f16x8 a1 = *(const f16x8*)(ab + 1024);
        FRAG3(aRm, aRr, w, ks) FRAG3(aZm, aZr, 8 + w, ks)
      }
#pragma unroll 8
      for (int ks = 4; ks < KSTEPS; ++ks) {
        const char* ab = smem + (size_t)((ks - 4) * 4 + kh5) * 512 + l31 * 16;
        f16x8 a0 = *(const f16x8*)(ab);
        f16x8 a1 = *(const f16x8*)(ab + 1024);
        FRAG3(aRm, aRr, w, ks) FRAG3(aZm, aZr, 8 + w, ks)
      }
#pragma unroll
      for (int j = 0; j < 16; ++j) {
        rrv[j] = sigm_f(aRm[j] + aRr[j] * RINV + biR + bhR);
        zzv[j] = sigm_f(aZm[j] + aZr[j] * RINV + biZ + bhZ);
      }
    }
    f32x16 aNxm = (f32x16)0.f, aNxr = (f32x16)0.f;
    f32x16 aNhm = (f32x16)0.f, aNhr = (f32x16)0.f;
#pragma unroll
    for (int ks = 0; ks < 4; ++ks) {
      const char* ab = smem + 32768 + (size_t)(ks * 4 + kh5) * 512 + l31 * 16;
      f16x8 a0 = *(const f16x8*)(ab);
      f16x8 a1 = *(const f16x8*)(ab + 1024);
      FRAG3(aNxm, aNxr, 16 + w, ks)
    }
#pragma unroll 8
    for (int ks = 4; ks < KSTEPS; ++ks) {
      const char* ab = smem + (size_t)((ks - 4) * 4 + kh5) * 512 + l31 * 16;
      f16x8 a0 = *(const f16x8*)(ab);
      f16x8 a1 = *(const f16x8*)(ab + 1024);
      FRAG3(aNhm, aNhr, 16 + w, ks)
    }
    __syncthreads();

    const bool lastT = (t == TT - 1);
#pragma unroll
    for (int j = 0; j < 16; ++j) {
      int row = (j & 3) + ((j >> 2) << 3) + kh5 * 4;
      float hold = glh[row * GLHS + d];
      float Nx = aNxm[j] + aNxr[j] * RINV;
      float Nh = aNhm[j] + aNhr[j] * RINV;
      float nn = tanh_f(Nx + biN + rrv[j] * (Nh + bhN));
      float hnew = (1.f - zzv[j]) * nn + zzv[j] * hold;
      glh[row * GLHS + d] = hnew;
      if (lastT) hf_out[(size_t)(row0 + row) * HH + d] = hnew;
    }
    __syncthreads();

    if (!lastT) {
#pragma unroll
      for (int i = 0; i < 2; ++i) {
        int u = tid + i * 512;
        int prow = u & 31, kunit = u >> 5;
        const float* gsrc = glh + prow * GLHS + kunit * 8;
        float4 v0 = *(const float4*)(gsrc);
        float4 v1 = *(const float4*)(gsrc + 4);
        _Float16 m[8], r[8];
        split2h(v0.x, m[0], r[0]); split2h(v0.y, m[1], r[1]);
        split2h(v0.z, m[2], r[2]); split2h(v0.w, m[3], r[3]);
        split2h(v1.x, m[4], r[4]); split2h(v1.y, m[5], r[5]);
        split2h(v1.z, m[6], r[6]); split2h(v1.w, m[7], r[7]);
        int hks = kunit >> 1, kh = kunit & 1;
        char* basep = smem + (size_t)(hks * 4 + kh) * 512 + prow * 16;
        *(f16x8*)(basep) = *(f16x8*)m;
        *(f16x8*)(basep + 1024) = *(f16x8*)r;
      }
    }
  }
#undef FRAG3
}

// ---------------- PRNG (threefry_partitionable=True semantics) ----------------
__global__ void k_prng_setup(uint32_t* sk) {
  uint32_t k0, k1, s0, s1, t0, t1;
  tf2x32(0u, 7u, 0u, 0u, k0, k1);
  tf2x32(0u, 7u, 0u, 1u, s0, s1);
  tf2x32(k0, k1, 0u, 1u, t0, t1);
  sk[0] = s0; sk[1] = s1;
  sk[2] = t0; sk[3] = t1;
}

__global__ void k_genkeys(const uint32_t* __restrict__ sk, int which,
                          uint32_t* __restrict__ keys) {
  int i = blockIdx.x * blockDim.x + threadIdx.x;
  if (i < BN) {
    uint32_t o0, o1;
    tf2x32(sk[which * 2], sk[which * 2 + 1], 0u, (uint32_t)i, o0, o1);
    keys[i] = o0 ^ o1;
  }
}

// stable rank sort, tiled: 512 blocks x 16 elements, 16 threads/element
#define RSE 16
__global__ __launch_bounds__(256) void k_ranksort(const uint32_t* __restrict__ keys,
                                                  const int* __restrict__ vin,
                                                  int* __restrict__ vout) {
  __shared__ uint32_t skey[BN];
  __shared__ int psum[RSE][17];
  const int tid = threadIdx.x;
  const int g = tid >> 4;
  const int l = tid & 15;
  const int gi = blockIdx.x * RSE + g;
  for (int i = tid; i < BN; i += 256) skey[i] = keys[i];
  __syncthreads();
  const uint32_t ki = skey[gi];
  int rank = 0;
#pragma unroll 8
  for (int j = l; j < BN; j += 16) {
    uint32_t kj = skey[j];
    rank += (kj < ki) || (kj == ki && j < gi);
  }
  psum[g][l] = rank;
  __syncthreads();
  if (l == 0) {
    int r = 0;
#pragma unroll
    for (int tt = 0; tt < 16; ++tt) r += psum[g][tt];
    vout[r] = vin ? vin[gi] : gi;
  }
}

// ---------------- k-means ----------------
__global__ void k_init_centers(const float* __restrict__ h, const int* __restrict__ vals2,
                               float* __restrict__ centers, double* __restrict__ cnorm) {
  const int c = blockIdx.x, d = threadIdx.x;
  const int src = vals2[c];
  float v = h[(size_t)src * HH + d];
  centers[c * HH + d] = v;
  __shared__ double red[HH];
  red[d] = (double)v * (double)v;
  __syncthreads();
  for (int s = 128; s > 0; s >>= 1) {
    if (d < s) red[d] += red[d + s];
    __syncthreads();
  }
  if (d == 0) cnorm[c] = red[0];
}

// fused assign + partial-update: 256 blocks x 256 thr, 32 rows/block.
__global__ __launch_bounds__(256) void k_fa(const float* __restrict__ h,
                                            const float* __restrict__ centers,
                                            const double* __restrict__ cnorm,
                                            double* __restrict__ psum,
                                            float* __restrict__ pcnt) {
  __shared__ float sc[KK * HH];
  __shared__ double sn[KK];
  __shared__ int lcode[FAB];
  __shared__ double acc[KK * HH];
  const int tid = threadIdx.x;
  for (int i = tid; i < KK * HH; i += 256) { sc[i] = centers[i]; acc[i] = 0.0; }
  if (tid < KK) sn[tid] = cnorm[tid];
  __syncthreads();
  const int row0 = blockIdx.x * FAB;
  const int r = tid >> 3, seg = tid & 7;
  const int grow = row0 + r;
  const float4* hp = (const float4*)&h[(size_t)grow * HH + seg * 32];
  const float* schp = sc + seg * 32;
  double dot[KK] = {};
  double xn = 0.0;
#pragma unroll
  for (int k4 = 0; k4 < 8; ++k4) {
    float4 xv = hp[k4];
    double x0 = xv.x, x1 = xv.y, x2 = xv.z, x3 = xv.w;
    xn += x0 * x0 + x1 * x1 + x2 * x2 + x3 * x3;
#pragma unroll
    for (int c = 0; c < KK; ++c) {
      float4 cv = *(const float4*)&schp[c * HH + k4 * 4];
      dot[c] += x0 * cv.x + x1 * cv.y + x2 * cv.z + x3 * cv.w;
    }
  }
  xn += __shfl_xor(xn, 1); xn += __shfl_xor(xn, 2); xn += __shfl_xor(xn, 4);
#pragma unroll
  for (int c = 0; c < KK; ++c) {
    dot[c] += __shfl_xor(dot[c], 1);
    dot[c] += __shfl_xor(dot[c], 2);
    dot[c] += __shfl_xor(dot[c], 4);
  }
  if (seg == 0) {
    int best = 0;
    double bd = xn - 2.0 * dot[0] + sn[0];
#pragma unroll
    for (int c = 1; c < KK; ++c) {
      double d2 = xn - 2.0 * dot[c] + sn[c];
      if (d2 < bd) { bd = d2; best = c; }
    }
    lcode[r] = best;
  }
  __syncthreads();
  const int d = tid;
  for (int p = 0; p < FAB; ++p)
    acc[lcode[p] * HH + d] += (double)h[(size_t)(row0 + p) * HH + d];
  if (tid < KK) {
    float cnt = 0.f;
    for (int p = 0; p < FAB; ++p) cnt += (lcode[p] == tid) ? 1.f : 0.f;
    pcnt[blockIdx.x * KK + tid] = cnt;
  }
  for (int c = 0; c < KK; ++c)
    psum[((size_t)blockIdx.x * KK + c) * HH + d] = acc[c * HH + d];
}

// parallel final update: grid KK x 1024 thr; 4-way b-split, q-ordered combine.
__global__ __launch_bounds__(1024) void k_upd_final(const double* __restrict__ psum,
                                                    const float* __restrict__ pcnt,
                                                    float* __restrict__ centers,
                                                    double* __restrict__ cnorm) {
  const int c = blockIdx.x;
  const int tid = threadIdx.x;
  const int d = tid & 255, q = tid >> 8;
  __shared__ double part[4][HH];
  __shared__ float cpart[4];
  __shared__ double red[HH];
  double s = 0.0;
  for (int b = q * (NPART / 4); b < (q + 1) * (NPART / 4); ++b)
    s += psum[((size_t)b * KK + c) * HH + d];
  part[q][d] = s;
  if (d == 0) {
    float cq = 0.f;
    for (int b = q * (NPART / 4); b < (q + 1) * (NPART / 4); ++b)
      cq += pcnt[b * KK + c];
    cpart[q] = cq;
  }
  __syncthreads();
  float v = 0.f;
  if (q == 0) {
    double st = part[0][d] + part[1][d] + part[2][d] + part[3][d];
    float cnt = cpart[0] + cpart[1] + cpart[2] + cpart[3];   // exact ints
    if (cnt <= 0.5f) cnt = 1.f;
    v = (float)(st / (double)cnt);
    centers[c * HH + d] = v;
    red[d] = (double)v * (double)v;
  }
  __syncthreads();
  for (int s2 = 128; s2 > 0; s2 >>= 1) {
    if (q == 0 && d < s2) red[d] += red[d + s2];
    __syncthreads();
  }
  if (tid == 0) cnorm[c] = red[0];
}

// ---------------- gumbel hard assignment (f64 decisions) ----------------
__global__ __launch_bounds__(128) void k_gumbel(const float* __restrict__ h,
                                                const float* __restrict__ centers,
                                                int* __restrict__ codeg) {
  __shared__ float sc[KK * HH];
  const int tid = threadIdx.x;
  for (int idx = tid; idx < KK * HH; idx += 128) sc[idx] = centers[idx];
  __syncthreads();
  const int b = blockIdx.x * 128 + tid;
  const float4* hp = (const float4*)&h[(size_t)b * HH];
  double acc[KK] = {};
  for (int k4 = 0; k4 < HH / 4; ++k4) {
    float4 xv = hp[k4];
    double x0 = xv.x, x1 = xv.y, x2 = xv.z, x3 = xv.w;
#pragma unroll
    for (int c = 0; c < KK; ++c) {
      float4 cv = *(const float4*)&sc[c * HH + k4 * 4];
      acc[c] += x0 * cv.x + x1 * cv.y + x2 * cv.z + x3 * cv.w;
    }
  }
  int best = 0;
  double bv = -1e300;
#pragma unroll
  for (int c = 0; c < KK; ++c) {
    double e = acc[c] > 0.0 ? acc[c] : 0.0;
    uint32_t j = (uint32_t)(b * KK + c);
    uint32_t o0, o1;
    tf2x32(0u, 42u, 0u, j, o0, o1);
    double U = (double)bits_to_unit(o0 ^ o1);
    double g = -log(-log(U + 1e-20) + 1e-20);
    double v = e + g;
    if (v > bv) { bv = v; best = c; }
  }
  codeg[b] = best;
}

// ---------------- GCN layer (adj = I) ----------------
__global__ void k_gcn(const float* __restrict__ in, const float* __restrict__ w,
                      const float* __restrict__ bias, float* __restrict__ out) {
  const int c = blockIdx.x, d = threadIdx.x;
  __shared__ float si[HH];
  si[d] = in[c * HH + d];
  __syncthreads();
  float acc = 0.f;
  for (int k = 0; k < HH; ++k) acc += si[k] * w[k * HH + d];
  acc += bias[d];
  out[c * HH + d] = acc > 0.f ? acc : 0.f;
}

// ---------------- final blend (f32 output) ----------------
__global__ __launch_bounds__(256) void k_final(const float* __restrict__ h,
                                               const float* __restrict__ h2,
                                               const int* __restrict__ codeg,
                                               const float* __restrict__ w1,
                                               const float* __restrict__ w1b,
                                               const float* __restrict__ w2,
                                               const float* __restrict__ w2b,
                                               float* __restrict__ out) {
  const int b = blockIdx.x, d = threadIdx.x;
  const int cg = codeg[b];
  const float cd = h2[cg * HH + d];
  const float hd = h[(size_t)b * HH + d];
  __shared__ float r1[HH], r2[HH];
  __shared__ float wan_s;
  r1[d] = cd * w1[d];
  r2[d] = hd * w2[d];
  __syncthreads();
  for (int s = 128; s > 0; s >>= 1) {
    if (d < s) { r1[d] += r1[d + s]; r2[d] += r2[d + s]; }
    __syncthreads();
  }
  if (d == 0) {
    float wa = 1.f / (1.f + expf(-(r1[0] + w1b[0])));
    float wb = 1.f / (1.f + expf(-(r2[0] + w2b[0])));
    wan_s = wa / (wa + wb);
  }
  __syncthreads();
  float wan = wan_s;
  out[(size_t)b * HH + d] = wan * cd + (1.f - wan) * hd;
}

// ---------------- launch ----------------
extern "C" void kernel_launch(void* const* d_in, const int* in_sizes, int n_in,
                              void* d_out, int out_size, void* d_ws, size_t ws_size,
                              hipStream_t stream) {
  const float* x   = (const float*)d_in[0];
  const float* wih = (const float*)d_in[1];
  const float* whh = (const float*)d_in[2];
  const float* bih = (const float*)d_in[3];
  const float* bhh = (const float*)d_in[4];
  const float* g1w = (const float*)d_in[5];
  const float* g1b = (const float*)d_in[6];
  const float* g2w = (const float*)d_in[7];
  const float* g2b = (const float*)d_in[8];
  const float* w1w = (const float*)d_in[9];
  const float* w1b = (const float*)d_in[10];
  const float* w2w = (const float*)d_in[11];
  const float* w2b = (const float*)d_in[12];
  float* out = (float*)d_out;

  char* wsb = (char*)d_ws;
  size_t off = 0;
  auto alloc = [&](size_t bytes) {
    void* p = wsb + off;
    off += (bytes + 255) & ~(size_t)255;
    return p;
  };
  float* hf0      = (float*)alloc((size_t)BN * HH * 4);
  char*  wpk4     = (char*)alloc((size_t)KSTEPS * 24 * 2 * 64 * 16);
  float* centers  = (float*)alloc(KK * HH * 4);
  double* cnorm   = (double*)alloc(KK * 8);
  int*   codeg    = (int*)alloc(BN * 4);
  uint32_t* keys  = (uint32_t*)alloc(BN * 4);
  int*   vals1    = (int*)alloc(BN * 4);
  int*   vals2    = (int*)alloc(BN * 4);
  uint32_t* sk    = (uint32_t*)alloc(4 * 4);
  double* psum    = (double*)alloc((size_t)NPART * KK * HH * 8);
  float* pcnt     = (float*)alloc(NPART * KK * 4);
  float* hh1      = (float*)alloc(KK * HH * 4);
  float* hh2      = (float*)alloc(KK * HH * 4);

  k_pack4<<<(KSTEPS * 24 * 2 * 64 + 255) / 256, 256, 0, stream>>>(wih, whh, wpk4);
  k_gru_v8<<<BN / 32, 512, 0, stream>>>(x, wpk4, bih, bhh, hf0);
  float* h = hf0;

  k_prng_setup<<<1, 1, 0, stream>>>(sk);
  k_genkeys<<<32, 256, 0, stream>>>(sk, 0, keys);
  k_ranksort<<<BN / RSE, 256, 0, stream>>>(keys, (const int*)nullptr, vals1);
  k_genkeys<<<32, 256, 0, stream>>>(sk, 1, keys);
  k_ranksort<<<BN / RSE, 256, 0, stream>>>(keys, vals1, vals2);

  k_init_centers<<<KK, HH, 0, stream>>>(h, vals2, centers, cnorm);
  k_fa<<<NPART, 256, 0, stream>>>(h, centers, cnorm, psum, pcnt);
  for (int it = 0; it < KM_ITERS_N; ++it) {
    k_upd_final<<<KK, 1024, 0, stream>>>(psum, pcnt, centers, cnorm);
    k_fa<<<NPART, 256, 0, stream>>>(h, centers, cnorm, psum, pcnt);
  }
  k_upd_final<<<KK, 1024, 0, stream>>>(psum, pcnt, centers, cnorm);

  k_gumbel<<<BN / 128, 128, 0, stream>>>(h, centers, codeg);
  k_gcn<<<KK, HH, 0, stream>>>(centers, g1w, g1b, hh1);
  k_gcn<<<KK, HH, 0, stream>>>(hh1, g2w, g2b, hh2);
  k_final<<<BN, HH, 0, stream>>>(h, hh2, codeg, w1w, w1b, w2w, w2b, out);
}

// Round 21
// 3359.534 us; speedup vs baseline: 2.4953x; 1.0037x over previous
//
#include <hip/hip_runtime.h>
#include <hip/hip_bf16.h>
#include <stdint.h>

#define BN 8192
#define TT 128
#define II 64
#define HH 256
#define GG 768
#define KK 12
#define KM_ITERS_N 25
#define KSTEPS 20
#define FAB 32
#define NPART (BN/FAB)

typedef __attribute__((ext_vector_type(8))) _Float16 f16x8;
typedef __attribute__((ext_vector_type(4))) _Float16 f16x4;
typedef __attribute__((ext_vector_type(16))) float f32x16;

// ---------------- threefry2x32 (JAX-exact) ----------------
__device__ __forceinline__ uint32_t rotl32(uint32_t v, int d) {
  return (v << d) | (v >> (32 - d));
}
__device__ __forceinline__ void tf2x32(uint32_t k0, uint32_t k1,
                                       uint32_t x0, uint32_t x1,
                                       uint32_t& o0, uint32_t& o1) {
  uint32_t ks2 = k0 ^ k1 ^ 0x1BD11BDAu;
  x0 += k0; x1 += k1;
#define TFR(r) { x0 += x1; x1 = rotl32(x1, r); x1 ^= x0; }
  TFR(13); TFR(15); TFR(26); TFR(6);   x0 += k1;  x1 += ks2 + 1u;
  TFR(17); TFR(29); TFR(16); TFR(24);  x0 += ks2; x1 += k0 + 2u;
  TFR(13); TFR(15); TFR(26); TFR(6);   x0 += k0;  x1 += k1 + 3u;
  TFR(17); TFR(29); TFR(16); TFR(24);  x0 += k1;  x1 += ks2 + 4u;
  TFR(13); TFR(15); TFR(26); TFR(6);   x0 += ks2; x1 += k0 + 5u;
#undef TFR
  o0 = x0; o1 = x1;
}
__device__ __forceinline__ float bits_to_unit(uint32_t bits) {
  uint32_t u = (bits >> 9) | 0x3f800000u;
  return __uint_as_float(u) - 1.0f;
}

// ---------------- fp16 2-plane split (residual scaled by 4096) ----------------
#define RSCL 4096.f
#define RINV (1.f / 4096.f)
__device__ __forceinline__ void split2h(float v, _Float16& m, _Float16& r) {
  m = (_Float16)v;
  r = (_Float16)((v - (float)m) * RSCL);
}

// ---------------- fast gates (exp2-based; v_exp_f32 native) ----------------
__device__ __forceinline__ float sigm_f(float u) {
  return 1.f / (1.f + exp2f(u * -1.4426950408889634f));
}
__device__ __forceinline__ float tanh_f(float u) {
  return 1.f - 2.f / (1.f + exp2f(u * 2.8853900817779268f));
}

// ---------------- weight pack: [ks 20][cf 24][p 2][lane 64]*16B ----------------
__global__ void k_pack4(const float* __restrict__ wih, const float* __restrict__ whh,
                        char* __restrict__ wpk4) {
  int u = blockIdx.x * 256 + threadIdx.x;
  if (u >= KSTEPS * 24 * 2 * 64) return;
  int lane = u & 63; int rest = u >> 6;
  int p = rest & 1; rest >>= 1;
  int cf = rest % 24; int ks = rest / 24;
  int l31 = lane & 31, khalf = lane >> 5;
  int col = cf * 32 + l31;
  int gate = col >> 8, d = col & 255;
  int grow = gate * 256 + d;
  _Float16 s[8];
#pragma unroll
  for (int j = 0; j < 8; ++j) {
    int k = khalf * 8 + j;
    float wv = (ks < 4) ? wih[grow * II + ks * 16 + k]
                        : whh[grow * HH + (ks - 4) * 16 + k];
    _Float16 m, r;
    split2h(wv, m, r);
    s[j] = p ? r : m;
  }
  *(f16x8*)(wpk4 + (size_t)u * 16) = *(f16x8*)s;
}

// ---------------- persistent MFMA GRU v8 (fp16 2-plane, two-pass) ----------------
#define GLHS 260
#define GLB 40960

__global__ __launch_bounds__(512, 2) void k_gru_v8(
    const float* __restrict__ x, const char* __restrict__ wpk4,
    const float* __restrict__ bih, const float* __restrict__ bhh,
    float* __restrict__ hf_out) {
  __shared__ __align__(16) char smem[74240];
  float* glh = (float*)(smem + GLB);
  const int tid = threadIdx.x;
  const int w = tid >> 6;
  const int l = tid & 63, l31 = l & 31, kh5 = l >> 5;
  const int row0 = blockIdx.x * 32;

  {  // zero h planes (32 KB) + glh
    int4 z = {0, 0, 0, 0};
    int4* s4 = (int4*)smem;
#pragma unroll
    for (int i = 0; i < 4; ++i) s4[tid + i * 512] = z;
    for (int i = tid; i < 32 * GLHS; i += 512) glh[i] = 0.f;
  }
  const int d = w * 32 + l31;
  const float biR = bih[d],          bhR = bhh[d];
  const float biZ = bih[HH + d],     bhZ = bhh[HH + d];
  const float biN = bih[2 * HH + d], bhN = bhh[2 * HH + d];

  const int xrow = tid & 31, xko4 = tid >> 5;
  const float* xbase = x + (size_t)(row0 + xrow) * (TT * II) + xko4 * 4;
  float4 xreg = *(const float4*)xbase;
  __syncthreads();

#define FRAG3(ACCM, ACCR, CF, KS)                                                  \
    {                                                                              \
      const char* bf = wpk4 + (((size_t)(KS) * 24 + (CF)) * 2) * 1024 +            \
                       (size_t)l * 16;                                             \
      f16x8 b0 = *(const f16x8*)(bf);                                              \
      f16x8 b1 = *(const f16x8*)(bf + 1024);                                       \
      ACCM = __builtin_amdgcn_mfma_f32_32x32x16_f16(a0, b0, ACCM, 0, 0, 0);        \
      ACCR = __builtin_amdgcn_mfma_f32_32x32x16_f16(a0, b1, ACCR, 0, 0, 0);        \
      ACCR = __builtin_amdgcn_mfma_f32_32x32x16_f16(a1, b0, ACCR, 0, 0, 0);        \
    }

  for (int t = 0; t < TT; ++t) {
    {
      _Float16 m[4], r[4];
      split2h(xreg.x, m[0], r[0]);
      split2h(xreg.y, m[1], r[1]);
      split2h(xreg.z, m[2], r[2]);
      split2h(xreg.w, m[3], r[3]);
      int xks = xko4 >> 2, kh = (xko4 >> 1) & 1, sub = (xko4 & 1) * 8;
      char* b0 = smem + 32768 + (size_t)(xks * 4 + kh) * 512 + xrow * 16 + sub;
      *(f16x4*)b0 = *(f16x4*)m;
      *(f16x4*)(b0 + 1024) = *(f16x4*)r;
    }
    if (t + 1 < TT) xreg = *(const float4*)(xbase + (size_t)(t + 1) * II);
    __syncthreads();

    f32x16 rrv, zzv;
    {
      f32x16 aRm = (f32x16)0.f, aRr = (f32x16)0.f;
      f32x16 aZm = (f32x16)0.f, aZr = (f32x16)0.f;
#pragma unroll
      for (int ks = 0; ks < 4; ++ks) {
        const char* ab = smem + 32768 + (size_t)(ks * 4 + kh5) * 512 + l31 * 16;
        f16x8 a0 = *(const f16x8*)(ab);
        f16x8 a1 = *(const f16x8*)(ab + 1024);
        FRAG3(aRm, aRr, w, ks) FRAG3(aZm, aZr, 8 + w, ks)
      }
#pragma unroll 8
      for (int ks = 4; ks < KSTEPS; ++ks) {
        const char* ab = smem + (size_t)((ks - 4) * 4 + kh5) * 512 + l31 * 16;
        f16x8 a0 = *(const f16x8*)(ab);
        f16x8 a1 = *(const f16x8*)(ab + 1024);
        FRAG3(aRm, aRr, w, ks) FRAG3(aZm, aZr, 8 + w, ks)
      }
#pragma unroll
      for (int j = 0; j < 16; ++j) {
        rrv[j] = sigm_f(aRm[j] + aRr[j] * RINV + biR + bhR);
        zzv[j] = sigm_f(aZm[j] + aZr[j] * RINV + biZ + bhZ);
      }
    }
    f32x16 aNxm = (f32x16)0.f, aNxr = (f32x16)0.f;
    f32x16 aNhm = (f32x16)0.f, aNhr = (f32x16)0.f;
#pragma unroll
    for (int ks = 0; ks < 4; ++ks) {
      const char* ab = smem + 32768 + (size_t)(ks * 4 + kh5) * 512 + l31 * 16;
      f16x8 a0 = *(const f16x8*)(ab);
      f16x8 a1 = *(const f16x8*)(ab + 1024);
      FRAG3(aNxm, aNxr, 16 + w, ks)
    }
#pragma unroll 8
    for (int ks = 4; ks < KSTEPS; ++ks) {
      const char* ab = smem + (size_t)((ks - 4) * 4 + kh5) * 512 + l31 * 16;
      f16x8 a0 = *(const f16x8*)(ab);
      f16x8 a1 = *(const f16x8*)(ab + 1024);
      FRAG3(aNhm, aNhr, 16 + w, ks)
    }
    __syncthreads();

    const bool lastT = (t == TT - 1);
#pragma unroll
    for (int j = 0; j < 16; ++j) {
      int row = (j & 3) + ((j >> 2) << 3) + kh5 * 4;
      float hold = glh[row * GLHS + d];
      float Nx = aNxm[j] + aNxr[j] * RINV;
      float Nh = aNhm[j] + aNhr[j] * RINV;
      float nn = tanh_f(Nx + biN + rrv[j] * (Nh + bhN));
      float hnew = (1.f - zzv[j]) * nn + zzv[j] * hold;
      glh[row * GLHS + d] = hnew;
      if (lastT) hf_out[(size_t)(row0 + row) * HH + d] = hnew;
    }
    __syncthreads();

    if (!lastT) {
#pragma unroll
      for (int i = 0; i < 2; ++i) {
        int u = tid + i * 512;
        int prow = u & 31, kunit = u >> 5;
        const float* gsrc = glh + prow * GLHS + kunit * 8;
        float4 v0 = *(const float4*)(gsrc);
        float4 v1 = *(const float4*)(gsrc + 4);
        _Float16 m[8], r[8];
        split2h(v0.x, m[0], r[0]); split2h(v0.y, m[1], r[1]);
        split2h(v0.z, m[2], r[2]); split2h(v0.w, m[3], r[3]);
        split2h(v1.x, m[4], r[4]); split2h(v1.y, m[5], r[5]);
        split2h(v1.z, m[6], r[6]); split2h(v1.w, m[7], r[7]);
        int hks = kunit >> 1, kh = kunit & 1;
        char* basep = smem + (size_t)(hks * 4 + kh) * 512 + prow * 16;
        *(f16x8*)(basep) = *(f16x8*)m;
        *(f16x8*)(basep + 1024) = *(f16x8*)r;
      }
    }
  }
#undef FRAG3
}

// ---------------- PRNG (threefry_partitionable=True semantics) ----------------
__global__ void k_prng_setup(uint32_t* sk) {
  uint32_t k0, k1, s0, s1, t0, t1;
  tf2x32(0u, 7u, 0u, 0u, k0, k1);
  tf2x32(0u, 7u, 0u, 1u, s0, s1);
  tf2x32(k0, k1, 0u, 1u, t0, t1);
  sk[0] = s0; sk[1] = s1;
  sk[2] = t0; sk[3] = t1;
}

__global__ void k_genkeys(const uint32_t* __restrict__ sk, int which,
                          uint32_t* __restrict__ keys) {
  int i = blockIdx.x * blockDim.x + threadIdx.x;
  if (i < BN) {
    uint32_t o0, o1;
    tf2x32(sk[which * 2], sk[which * 2 + 1], 0u, (uint32_t)i, o0, o1);
    keys[i] = o0 ^ o1;
  }
}

// stable rank sort, tiled: 512 blocks x 16 elements, 16 threads/element
#define RSE 16
__global__ __launch_bounds__(256) void k_ranksort(const uint32_t* __restrict__ keys,
                                                  const int* __restrict__ vin,
                                                  int* __restrict__ vout) {
  __shared__ uint32_t skey[BN];
  __shared__ int psum[RSE][17];
  const int tid = threadIdx.x;
  const int g = tid >> 4;
  const int l = tid & 15;
  const int gi = blockIdx.x * RSE + g;
  for (int i = tid; i < BN; i += 256) skey[i] = keys[i];
  __syncthreads();
  const uint32_t ki = skey[gi];
  int rank = 0;
#pragma unroll 8
  for (int j = l; j < BN; j += 16) {
    uint32_t kj = skey[j];
    rank += (kj < ki) || (kj == ki && j < gi);
  }
  psum[g][l] = rank;
  __syncthreads();
  if (l == 0) {
    int r = 0;
#pragma unroll
    for (int tt = 0; tt < 16; ++tt) r += psum[g][tt];
    vout[r] = vin ? vin[gi] : gi;
  }
}

// ---------------- k-means ----------------
__global__ void k_init_centers(const float* __restrict__ h, const int* __restrict__ vals2,
                               float* __restrict__ centers, double* __restrict__ cnorm) {
  const int c = blockIdx.x, d = threadIdx.x;
  const int src = vals2[c];
  float v = h[(size_t)src * HH + d];
  centers[c * HH + d] = v;
  __shared__ double red[HH];
  red[d] = (double)v * (double)v;
  __syncthreads();
  for (int s = 128; s > 0; s >>= 1) {
    if (d < s) red[d] += red[d + s];
    __syncthreads();
  }
  if (d == 0) cnorm[c] = red[0];
}

// fused assign + partial-update: 256 blocks x 256 thr, 32 rows/block.
__global__ __launch_bounds__(256) void k_fa(const float* __restrict__ h,
                                            const float* __restrict__ centers,
                                            const double* __restrict__ cnorm,
                                            double* __restrict__ psum,
                                            float* __restrict__ pcnt) {
  __shared__ float sc[KK * HH];
  __shared__ double sn[KK];
  __shared__ int lcode[FAB];
  __shared__ double acc[KK * HH];
  const int tid = threadIdx.x;
  for (int i = tid; i < KK * HH; i += 256) { sc[i] = centers[i]; acc[i] = 0.0; }
  if (tid < KK) sn[tid] = cnorm[tid];
  __syncthreads();
  const int row0 = blockIdx.x * FAB;
  const int r = tid >> 3, seg = tid & 7;
  const int grow = row0 + r;
  const float4* hp = (const float4*)&h[(size_t)grow * HH + seg * 32];
  const float* schp = sc + seg * 32;
  double dot[KK] = {};
  double xn = 0.0;
#pragma unroll
  for (int k4 = 0; k4 < 8; ++k4) {
    float4 xv = hp[k4];
    double x0 = xv.x, x1 = xv.y, x2 = xv.z, x3 = xv.w;
    xn += x0 * x0 + x1 * x1 + x2 * x2 + x3 * x3;
#pragma unroll
    for (int c = 0; c < KK; ++c) {
      float4 cv = *(const float4*)&schp[c * HH + k4 * 4];
      dot[c] += x0 * cv.x + x1 * cv.y + x2 * cv.z + x3 * cv.w;
    }
  }
  xn += __shfl_xor(xn, 1); xn += __shfl_xor(xn, 2); xn += __shfl_xor(xn, 4);
#pragma unroll
  for (int c = 0; c < KK; ++c) {
    dot[c] += __shfl_xor(dot[c], 1);
    dot[c] += __shfl_xor(dot[c], 2);
    dot[c] += __shfl_xor(dot[c], 4);
  }
  if (seg == 0) {
    int best = 0;
    double bd = xn - 2.0 * dot[0] + sn[0];
#pragma unroll
    for (int c = 1; c < KK; ++c) {
      double d2 = xn - 2.0 * dot[c] + sn[c];
      if (d2 < bd) { bd = d2; best = c; }
    }
    lcode[r] = best;
  }
  __syncthreads();
  const int d = tid;
  for (int p = 0; p < FAB; ++p)
    acc[lcode[p] * HH + d] += (double)h[(size_t)(row0 + p) * HH + d];
  if (tid < KK) {
    float cnt = 0.f;
    for (int p = 0; p < FAB; ++p) cnt += (lcode[p] == tid) ? 1.f : 0.f;
    pcnt[blockIdx.x * KK + tid] = cnt;
  }
  for (int c = 0; c < KK; ++c)
    psum[((size_t)blockIdx.x * KK + c) * HH + d] = acc[c * HH + d];
}

// parallel final update: grid KK x 1024 thr; 4-way b-split, q-ordered combine.
__global__ __launch_bounds__(1024) void k_upd_final(const double* __restrict__ psum,
                                                    const float* __restrict__ pcnt,
                                                    float* __restrict__ centers,
                                                    double* __restrict__ cnorm) {
  const int c = blockIdx.x;
  const int tid = threadIdx.x;
  const int d = tid & 255, q = tid >> 8;
  __shared__ double part[4][HH];
  __shared__ float cpart[4];
  __shared__ double red[HH];
  double s = 0.0;
  for (int b = q * (NPART / 4); b < (q + 1) * (NPART / 4); ++b)
    s += psum[((size_t)b * KK + c) * HH + d];
  part[q][d] = s;
  if (d == 0) {
    float cq = 0.f;
    for (int b = q * (NPART / 4); b < (q + 1) * (NPART / 4); ++b)
      cq += pcnt[b * KK + c];
    cpart[q] = cq;
  }
  __syncthreads();
  float v = 0.f;
  if (q == 0) {
    double st = part[0][d] + part[1][d] + part[2][d] + part[3][d];
    float cnt = cpart[0] + cpart[1] + cpart[2] + cpart[3];
    if (cnt <= 0.5f) cnt = 1.f;
    v = (float)(st / (double)cnt);
    centers[c * HH + d] = v;
    red[d] = (double)v * (double)v;
  }
  __syncthreads();
  for (int s2 = 128; s2 > 0; s2 >>= 1) {
    if (q == 0 && d < s2) red[d] += red[d + s2];
    __syncthreads();
  }
  if (tid == 0) cnorm[c] = red[0];
}

// ---------------- gumbel hard assignment (f64 decisions) ----------------
__global__ __launch_bounds__(128) void k_gumbel(const float* __restrict__ h,
                                                const float* __restrict__ centers,
                                                int* __restrict__ codeg) {
  __shared__ float sc[KK * HH];
  const int tid = threadIdx.x;
  for (int idx = tid; idx < KK * HH; idx += 128) sc[idx] = centers[idx];
  __syncthreads();
  const int b = blockIdx.x * 128 + tid;
  const float4* hp = (const float4*)&h[(size_t)b * HH];
  double acc[KK] = {};
  for (int k4 = 0; k4 < HH / 4; ++k4) {
    float4 xv = hp[k4];
    double x0 = xv.x, x1 = xv.y, x2 = xv.z, x3 = xv.w;
#pragma unroll
    for (int c = 0; c < KK; ++c) {
      float4 cv = *(const float4*)&sc[c * HH + k4 * 4];
      acc[c] += x0 * cv.x + x1 * cv.y + x2 * cv.z + x3 * cv.w;
    }
  }
  int best = 0;
  double bv = -1e300;
#pragma unroll
  for (int c = 0; c < KK; ++c) {
    double e = acc[c] > 0.0 ? acc[c] : 0.0;
    uint32_t j = (uint32_t)(b * KK + c);
    uint32_t o0, o1;
    tf2x32(0u, 42u, 0u, j, o0, o1);
    double U = (double)bits_to_unit(o0 ^ o1);
    double g = -log(-log(U + 1e-20) + 1e-20);
    double v = e + g;
    if (v > bv) { bv = v; best = c; }
  }
  codeg[b] = best;
}

// ---------------- GCN layer (adj = I) ----------------
__global__ void k_gcn(const float* __restrict__ in, const float* __restrict__ w,
                      const float* __restrict__ bias, float* __restrict__ out) {
  const int c = blockIdx.x, d = threadIdx.x;
  __shared__ float si[HH];
  si[d] = in[c * HH + d];
  __syncthreads();
  float acc = 0.f;
  for (int k = 0; k < HH; ++k) acc += si[k] * w[k * HH + d];
  acc += bias[d];
  out[c * HH + d] = acc > 0.f ? acc : 0.f;
}

// ---------------- final blend (f32 output) ----------------
__global__ __launch_bounds__(256) void k_final(const float* __restrict__ h,
                                               const float* __restrict__ h2,
                                               const int* __restrict__ codeg,
                                               const float* __restrict__ w1,
                                               const float* __restrict__ w1b,
                                               const float* __restrict__ w2,
                                               const float* __restrict__ w2b,
                                               float* __restrict__ out) {
  const int b = blockIdx.x, d = threadIdx.x;
  const int cg = codeg[b];
  const float cd = h2[cg * HH + d];
  const float hd = h[(size_t)b * HH + d];
  __shared__ float r1[HH], r2[HH];
  __shared__ float wan_s;
  r1[d] = cd * w1[d];
  r2[d] = hd * w2[d];
  __syncthreads();
  for (int s = 128; s > 0; s >>= 1) {
    if (d < s) { r1[d] += r1[d + s]; r2[d] += r2[d + s]; }
    __syncthreads();
  }
  if (d == 0) {
    float wa = 1.f / (1.f + expf(-(r1[0] + w1b[0])));
    float wb = 1.f / (1.f + expf(-(r2[0] + w2b[0])));
    wan_s = wa / (wa + wb);
  }
  __syncthreads();
  float wan = wan_s;
  out[(size_t)b * HH + d] = wan * cd + (1.f - wan) * hd;
}

// ---------------- launch ----------------
extern "C" void kernel_launch(void* const* d_in, const int* in_sizes, int n_in,
                              void* d_out, int out_size, void* d_ws, size_t ws_size,
                              hipStream_t stream) {
  const float* x   = (const float*)d_in[0];
  const float* wih = (const float*)d_in[1];
  const float* whh = (const float*)d_in[2];
  const float* bih = (const float*)d_in[3];
  const float* bhh = (const float*)d_in[4];
  const float* g1w = (const float*)d_in[5];
  const float* g1b = (const float*)d_in[6];
  const float* g2w = (const float*)d_in[7];
  const float* g2b = (const float*)d_in[8];
  const float* w1w = (const float*)d_in[9];
  const float* w1b = (const float*)d_in[10];
  const float* w2w = (const float*)d_in[11];
  const float* w2b = (const float*)d_in[12];
  float* out = (float*)d_out;

  char* wsb = (char*)d_ws;
  size_t off = 0;
  auto alloc = [&](size_t bytes) {
    void* p = wsb + off;
    off += (bytes + 255) & ~(size_t)255;
    return p;
  };
  float* hf0      = (float*)alloc((size_t)BN * HH * 4);
  char*  wpk4     = (char*)alloc((size_t)KSTEPS * 24 * 2 * 64 * 16);
  float* centers  = (float*)alloc(KK * HH * 4);
  double* cnorm   = (double*)alloc(KK * 8);
  int*   codeg    = (int*)alloc(BN * 4);
  uint32_t* keys  = (uint32_t*)alloc(BN * 4);
  int*   vals1    = (int*)alloc(BN * 4);
  int*   vals2    = (int*)alloc(BN * 4);
  uint32_t* sk    = (uint32_t*)alloc(4 * 4);
  double* psum    = (double*)alloc((size_t)NPART * KK * HH * 8);
  float* pcnt     = (float*)alloc(NPART * KK * 4);
  float* hh1      = (float*)alloc(KK * HH * 4);
  float* hh2      = (float*)alloc(KK * HH * 4);

  k_pack4<<<(KSTEPS * 24 * 2 * 64 + 255) / 256, 256, 0, stream>>>(wih, whh, wpk4);
  k_gru_v8<<<BN / 32, 512, 0, stream>>>(x, wpk4, bih, bhh, hf0);
  float* h = hf0;

  k_prng_setup<<<1, 1, 0, stream>>>(sk);
  k_genkeys<<<32, 256, 0, stream>>>(sk, 0, keys);
  k_ranksort<<<BN / RSE, 256, 0, stream>>>(keys, (const int*)nullptr, vals1);
  k_genkeys<<<32, 256, 0, stream>>>(sk, 1, keys);
  k_ranksort<<<BN / RSE, 256, 0, stream>>>(keys, vals1, vals2);

  k_init_centers<<<KK, HH, 0, stream>>>(h, vals2, centers, cnorm);
  k_fa<<<NPART, 256, 0, stream>>>(h, centers, cnorm, psum, pcnt);
  for (int it = 0; it < KM_ITERS_N; ++it) {
    k_upd_final<<<KK, 1024, 0, stream>>>(psum, pcnt, centers, cnorm);
    k_fa<<<NPART, 256, 0, stream>>>(h, centers, cnorm, psum, pcnt);
  }
  k_upd_final<<<KK, 1024, 0, stream>>>(psum, pcnt, centers, cnorm);

  k_gumbel<<<BN / 128, 128, 0, stream>>>(h, centers, codeg);
  k_gcn<<<KK, HH, 0, stream>>>(centers, g1w, g1b, hh1);
  k_gcn<<<KK, HH, 0, stream>>>(hh1, g2w, g2b, hh2);
  k_final<<<BN, HH, 0, stream>>>(h, hh2, codeg, w1w, w1b, w2w, w2b, out);
}